// Round 12
// baseline (193.810 us; speedup 1.0000x reference)
//
#include <hip/hip_runtime.h>
#include <hip/hip_bf16.h>

// Problem constants (B,S,M,D,H,DH = 2,1024,1024,1024,16,64)
#define B_ 2
#define S_ 1024
#define M_ 1024
#define D_ 1024
#define H_ 16
#define DH_ 64
#define K_ 2048
#define R_ 4095

// finite stand-in for -inf (avoids inf arithmetic under fast-math)
#define NEG_BIG (-1e30f)

typedef unsigned short u16;
typedef short short8 __attribute__((ext_vector_type(8)));
typedef float f32x4 __attribute__((ext_vector_type(4)));

__device__ __forceinline__ u16 f2bf(float f) {
  __hip_bfloat16 h = __float2bfloat16(f);
  return *reinterpret_cast<u16*>(&h);
}
__device__ __forceinline__ float bf2f(u16 u) {
  __hip_bfloat16 h;
  *reinterpret_cast<u16*>(&h) = u;
  return __bfloat162float(h);
}

// async global->LDS, 16B per lane; LDS dest = wave-uniform base + lane*16
__device__ __forceinline__ void gll16(const void* g, const void* l) {
  __builtin_amdgcn_global_load_lds(
      (const __attribute__((address_space(1))) unsigned int*)g,
      (__attribute__((address_space(3))) unsigned int*)l, 16, 0, 0);
}

__device__ __forceinline__ f32x4 mfma16(short8 a, short8 b, f32x4 c) {
  return __builtin_amdgcn_mfma_f32_16x16x32_bf16(a, b, c, 0, 0, 0);
}

// ---------------- fused prep: LN(concat) + 4x weight transpose + pos tiled cvt ----------
// posT layout: [b][g<144][oct<8][r<16][j<8] bf16 (136 groups written, 8 pad groups
// readable-garbage for the one-phase-ahead prefetch), so an attn pos-fragment load
// (rows g*16+lr, cols oct*8..+8) is ONE contiguous 1KB wave transaction.
__global__ __launch_bounds__(256) void prep_kernel(
    const float* __restrict__ hidden, const float* __restrict__ memory,
    const float* __restrict__ gamma, const float* __restrict__ beta,
    u16* __restrict__ cln,
    const float* __restrict__ W0, const float* __restrict__ W1,
    const float* __restrict__ W2, const float* __restrict__ W3,
    u16* __restrict__ O0, u16* __restrict__ O1,
    u16* __restrict__ O2, u16* __restrict__ O3,
    const float* __restrict__ pos, u16* __restrict__ posT) {
  __shared__ u16 tile[64][66];
  __shared__ float red[8];
  const int bx = blockIdx.x;
  const int t = threadIdx.x;

  if (bx < 4096) {  // LayerNorm row
    const int b = bx >> 11;
    const int idx = bx & (K_ - 1);
    const float* src = (idx < M_)
        ? memory + (size_t)(b * M_ + idx) * D_
        : hidden + (size_t)(b * S_ + (idx - M_)) * D_;
    const int lane = t & 63, w = t >> 6;
    float4 rv = ((const float4*)src)[t];
    float s = rv.x + rv.y + rv.z + rv.w;
    float ss = rv.x * rv.x + rv.y * rv.y + rv.z * rv.z + rv.w * rv.w;
#pragma unroll
    for (int m = 1; m < 64; m <<= 1) {
      s += __shfl_xor(s, m, 64);
      ss += __shfl_xor(ss, m, 64);
    }
    if (lane == 0) { red[w] = s; red[4 + w] = ss; }
    __syncthreads();
    s = red[0] + red[1] + red[2] + red[3];
    ss = red[4] + red[5] + red[6] + red[7];
    const float mu = s * (1.0f / D_);
    const float var = ss * (1.0f / D_) - mu * mu;
    const float rstd = rsqrtf(var + 1e-5f);
    float4 gv = ((const float4*)gamma)[t];
    float4 bv = ((const float4*)beta)[t];
    ushort4 ov;
    ov.x = f2bf((rv.x - mu) * rstd * gv.x + bv.x);
    ov.y = f2bf((rv.y - mu) * rstd * gv.y + bv.y);
    ov.z = f2bf((rv.z - mu) * rstd * gv.z + bv.z);
    ov.w = f2bf((rv.w - mu) * rstd * gv.w + bv.w);
    ((ushort4*)(cln + (size_t)bx * D_))[t] = ov;
    return;
  }
  if (bx < 5120) {  // weight transpose slab (float4-vectorized)
    const int z = (bx - 4096) >> 8;
    const int rem = (bx - 4096) & 255;
    const float* in; u16* out;
    switch (z) {
      case 0:  in = W0; out = O0; break;
      case 1:  in = W1; out = O1; break;
      case 2:  in = W2; out = O2; break;
      default: in = W3; out = O3; break;
    }
    const int k0 = (rem & 15) * 64, n0 = (rem >> 4) * 64;
    const int c4 = t & 15, rr = t >> 4;     // 16 float4-cols x 16 rows per pass
#pragma unroll
    for (int p = 0; p < 4; p++) {
      const int i = rr + p * 16;
      float4 v = *(const float4*)&in[(size_t)(k0 + i) * D_ + n0 + c4 * 4];
      tile[i][c4 * 4 + 0] = f2bf(v.x);
      tile[i][c4 * 4 + 1] = f2bf(v.y);
      tile[i][c4 * 4 + 2] = f2bf(v.z);
      tile[i][c4 * 4 + 3] = f2bf(v.w);
    }
    __syncthreads();
#pragma unroll
    for (int p = 0; p < 4; p++) {
      const int i = rr + p * 16;
      ushort4 o;
      o.x = tile[c4 * 4 + 0][i];
      o.y = tile[c4 * 4 + 1][i];
      o.z = tile[c4 * 4 + 2][i];
      o.w = tile[c4 * 4 + 3][i];
      *(ushort4*)&out[(size_t)(n0 + i) * D_ + k0 + c4 * 4] = o;
    }
    return;
  }
  // pos f32 -> bf16, tiled: u enumerates (b, g, r, oct); 136 groups of 16 rows per batch
  {
    const int u = (bx - 5120) * 256 + t;    // [0, 34816)
    const int oct = u & 7;
    const int r = (u >> 3) & 15;
    const int g = (u >> 7) % 136;
    const int b = u / 17408;                // 136*128
    const int row = g * 16 + r;             // <= 2175 < R_ (always in-bounds)
    const float* s = pos + ((size_t)b * R_ + row) * 64 + oct * 8;
    float4 v0 = ((const float4*)s)[0];
    float4 v1 = ((const float4*)s)[1];
    ushort4 oA, oB;
    oA.x = f2bf(v0.x); oA.y = f2bf(v0.y); oA.z = f2bf(v0.z); oA.w = f2bf(v0.w);
    oB.x = f2bf(v1.x); oB.y = f2bf(v1.y); oB.z = f2bf(v1.z); oB.w = f2bf(v1.w);
    u16* d = posT + (size_t)(b * 144 + g) * 1024 + oct * 128 + r * 8;  // 144-group stride
    ((ushort4*)d)[0] = oA;
    ((ushort4*)d)[1] = oB;
  }
}

// row r of the "hidden slice" view -> row of c_ln
__device__ __forceinline__ int maprow_hidden(int r) {
  return r + ((r >> 10) << 10) + M_;
}

// ---------------- QKV GEMM: BK=64, XOR-swizzled staging, 3 blocks/CU ----------------
// LDS-staged coalesced epilogue (R11-proven). V now written in FRAGMENT-TILED layout
// vf[bh][kt<32][d2<4][ch<8][lr<16][8]: attn's PV B-fragment (dh=d2*16+lr, keys ch*8..+8)
// becomes ONE contiguous 1KB wave transaction read directly from L2 (no LDS staging).
__global__ __launch_bounds__(256, 3) void gemm_qkv_kernel(
    const u16* __restrict__ A, const u16* __restrict__ Bt,
    u16* __restrict__ qb, u16* __restrict__ kb, u16* __restrict__ vf) {
  __shared__ __align__(16) u16 shm[128 * 132];   // 33 KB: As|Bs during loop, C-tile after
  u16* As = shm;                 // 128*64
  u16* Bs = shm + 8192;          // 128*64
  const int t = threadIdx.x;
  const int lane = t & 63, w = t >> 6;
  const int wm = w >> 1, wn = w & 1;
  const int qd = lane >> 4, lr = lane & 15;
  const int m0 = blockIdx.y * 128, n0 = blockIdx.x * 128;
  if (n0 < 1024 && !(m0 & 1024)) return;   // dead Q tiles (memory rows)

  const int swz = ((t & 7) ^ ((t >> 3) & 7)) * 8;  // source-chunk swizzle
  const int c0 = (qd ^ (lr & 7)) * 8;
  const int c1 = c0 ^ 32;
  const int row8 = (t >> 3) & 7;

  f32x4 acc[4][4];
#pragma unroll
  for (int mt = 0; mt < 4; mt++)
#pragma unroll
    for (int nt = 0; nt < 4; nt++) acc[mt][nt] = (f32x4){0.f, 0.f, 0.f, 0.f};

  for (int kt = 0; kt < 1024; kt += 64) {
#pragma unroll
    for (int p = 0; p < 4; p++) {
      const int ra = w * 32 + p * 8 + row8;
      gll16(A + (size_t)(m0 + ra) * 1024 + kt + swz, As + (w * 32 + p * 8) * 64);
      gll16(Bt + (size_t)(n0 + ra) * 1024 + kt + swz, Bs + (w * 32 + p * 8) * 64);
    }
    __syncthreads();
    short8 a0[4], a1[4], b0[4], b1[4];
#pragma unroll
    for (int mt = 0; mt < 4; mt++) {
      a0[mt] = *(const short8*)&As[(wm * 64 + mt * 16 + lr) * 64 + c0];
      a1[mt] = *(const short8*)&As[(wm * 64 + mt * 16 + lr) * 64 + c1];
    }
#pragma unroll
    for (int nt = 0; nt < 4; nt++) {
      b0[nt] = *(const short8*)&Bs[(wn * 64 + nt * 16 + lr) * 64 + c0];
      b1[nt] = *(const short8*)&Bs[(wn * 64 + nt * 16 + lr) * 64 + c1];
    }
#pragma unroll
    for (int mt = 0; mt < 4; mt++)
#pragma unroll
      for (int nt = 0; nt < 4; nt++) {
        acc[mt][nt] = mfma16(a0[mt], b0[nt], acc[mt][nt]);
        acc[mt][nt] = mfma16(a1[mt], b1[nt], acc[mt][nt]);
      }
    __syncthreads();
  }

  // ---- epilogue: stage C-tile (or C^T for V) into LDS, then coalesced stores ----
  const bool isV = (n0 >= 2048);
  if (!isV) {                    // Q (scaled) or K: row-major [row][col], pad 132
    const float sc = (n0 < 1024) ? 0.03125f : 1.0f;
#pragma unroll
    for (int mt = 0; mt < 4; mt++)
#pragma unroll
      for (int nt = 0; nt < 4; nt++) {
        const int row0 = wm * 64 + mt * 16 + qd * 4;
        const int col = wn * 64 + nt * 16 + lr;
#pragma unroll
        for (int r = 0; r < 4; r++)
          shm[(row0 + r) * 132 + col] = f2bf(acc[mt][nt][r] * sc);
      }
  } else {                       // V: transposed [nn][kk], ushort4 along kk
#pragma unroll
    for (int mt = 0; mt < 4; mt++)
#pragma unroll
      for (int nt = 0; nt < 4; nt++) {
        const int kk0 = wm * 64 + mt * 16 + qd * 4;
        const int nn = wn * 64 + nt * 16 + lr;
        ushort4 pk;
        pk.x = f2bf(acc[mt][nt][0]);
        pk.y = f2bf(acc[mt][nt][1]);
        pk.z = f2bf(acc[mt][nt][2]);
        pk.w = f2bf(acc[mt][nt][3]);
        *(ushort4*)&shm[nn * 132 + kk0] = pk;
      }
  }
  __syncthreads();
  // 2048 16B-chunks (128 rows x 16), 8 per thread; consecutive t -> contiguous runs
  const int bq = m0 >> 11;
#pragma unroll
  for (int i = 0; i < 8; i++) {
    const int flat = i * 256 + t;
    const int row = flat >> 4;
    const int ch = flat & 15;
    const ushort4 v0 = *(const ushort4*)&shm[row * 132 + ch * 8];
    const ushort4 v1 = *(const ushort4*)&shm[row * 132 + ch * 8 + 4];
    u16* dst;
    if (n0 < 1024) {
      const int qrow = (bq << 10) | ((m0 + row) & 1023);
      dst = qb + (size_t)qrow * 1024 + n0 + ch * 8;
    } else if (!isV) {
      const int key = (m0 + row) & (K_ - 1);
      dst = kb + (size_t)(bq * K_ + key) * 1024 + (n0 - 1024) + ch * 8;
    } else {
      // fragment-tiled vf: row = dh within 128-col block, chunk = 8 keys
      const int dhg = (n0 - 2048) + row;           // h*64 + dh within batch
      const int bh = (bq << 4) | (dhg >> 6);
      const int dh = dhg & 63;
      const int gk = (m0 & (K_ - 1)) + ch * 8;     // global key of this chunk
      const int ktile = gk >> 6;
      const int w6ch = (gk & 63) >> 3;
      const int d2 = dh >> 4, lrr = dh & 15;
      dst = vf + (size_t)bh * 131072 + (size_t)ktile * 4096
               + ((d2 * 8 + w6ch) * 16 + lrr) * 8;
    }
    short8 vv;
    *(ushort4*)&vv = v0;
    *(((ushort4*)&vv) + 1) = v1;
    *(short8*)dst = vv;          // one 16B store
  }
}

// ---------------- out GEMM: 128x64 tiles, BK=64, XOR-swizzled (qkv's proven pattern) ----
__global__ __launch_bounds__(256, 2) void out_gemm_kernel(
    const u16* __restrict__ A, const u16* __restrict__ Bt,
    const u16* __restrict__ resid, float* __restrict__ Cf) {
  __shared__ __align__(16) u16 As[128 * 64];   // 16 KB
  __shared__ __align__(16) u16 Bs[64 * 64];    // 8 KB
  const int t = threadIdx.x;
  const int lane = t & 63, w = t >> 6;
  const int wm = w >> 1, wn = w & 1;
  const int qd = lane >> 4, lr = lane & 15;
  const int m0 = blockIdx.y * 128, n0 = blockIdx.x * 64;

  const int swz = ((t & 7) ^ ((t >> 3) & 7)) * 8;  // source-chunk swizzle
  const int c0 = (qd ^ (lr & 7)) * 8;              // fragment-read chunk offsets
  const int c1 = c0 ^ 32;
  const int row8 = (t >> 3) & 7;

  f32x4 acc[4][2];
#pragma unroll
  for (int mt = 0; mt < 4; mt++)
#pragma unroll
    for (int nt = 0; nt < 2; nt++) acc[mt][nt] = (f32x4){0.f, 0.f, 0.f, 0.f};

  for (int kt = 0; kt < 1024; kt += 64) {
#pragma unroll
    for (int p = 0; p < 4; p++) {   // As rows 0..127
      const int ra = w * 32 + p * 8 + row8;
      gll16(A + (size_t)(m0 + ra) * 1024 + kt + swz, As + (w * 32 + p * 8) * 64);
    }
#pragma unroll
    for (int p = 0; p < 2; p++) {   // Bs rows 0..63
      const int rb = w * 16 + p * 8 + row8;
      gll16(Bt + (size_t)(n0 + rb) * 1024 + kt + swz, Bs + (w * 16 + p * 8) * 64);
    }
    __syncthreads();
    short8 a0[4], a1[4], b0[2], b1[2];
#pragma unroll
    for (int mt = 0; mt < 4; mt++) {
      a0[mt] = *(const short8*)&As[(wm * 64 + mt * 16 + lr) * 64 + c0];
      a1[mt] = *(const short8*)&As[(wm * 64 + mt * 16 + lr) * 64 + c1];
    }
#pragma unroll
    for (int nt = 0; nt < 2; nt++) {
      b0[nt] = *(const short8*)&Bs[(wn * 32 + nt * 16 + lr) * 64 + c0];
      b1[nt] = *(const short8*)&Bs[(wn * 32 + nt * 16 + lr) * 64 + c1];
    }
#pragma unroll
    for (int mt = 0; mt < 4; mt++)
#pragma unroll
      for (int nt = 0; nt < 2; nt++) {
        acc[mt][nt] = mfma16(a0[mt], b0[nt], acc[mt][nt]);
        acc[mt][nt] = mfma16(a1[mt], b1[nt], acc[mt][nt]);
      }
    __syncthreads();
  }

#pragma unroll
  for (int mt = 0; mt < 4; mt++)
#pragma unroll
    for (int nt = 0; nt < 2; nt++)
#pragma unroll
      for (int r = 0; r < 4; r++) {
        const int row = m0 + wm * 64 + mt * 16 + qd * 4 + r;
        const int col = n0 + wn * 32 + nt * 16 + lr;
        float v = acc[mt][nt][r] + bf2f(resid[(size_t)maprow_hidden(row) * 1024 + col]);
        Cf[(size_t)row * 1024 + col] = v;
      }
}

// ---------------- attention: KVBLK=128, V DIRECT FROM L2 (no LDS staging) --------------
// XCD-grouped remap keeps each (b,h)'s K/V L2-resident (R4: FETCH = unique bytes).
// V read per sub as 8 fully-coalesced 1KB fragment loads from fragment-tiled vf into
// registers (issued at sub start; QK+softmax covers L2 latency). Removes 4 gll16 +
// 16 ds_read_b128 per phase and 32 KB LDS (73728 -> 40960). grid (16, H, B).
__global__ __launch_bounds__(256, 2) void attn_kernel(
    const u16* __restrict__ qb, const u16* __restrict__ kb,
    const u16* __restrict__ vf, const u16* __restrict__ posT,
    u16* __restrict__ ab) {
  __shared__ __align__(16) u16 Ks[2][2][64 * 64];   // 32 KB (Ks[1][0] aliases Q pre-loop)
  __shared__ __align__(16) u16 Pt[4][16 * 64];      // 8 KB wave-private (XOR-swizzled)

  const int t = threadIdx.x;
  const int lane = t & 63, w = t >> 6;
  const int qd = lane >> 4, lr = lane & 15;

  // XCD-grouping remap (bijective on 512 blocks) — R4-proven
  const int flat = blockIdx.x + 16 * blockIdx.y + 256 * blockIdx.z;
  const int xcd = flat & 7;
  const int slot = flat >> 3;          // 0..63 within XCD
  const int gsub = slot >> 4;          // 0..3
  int qt = slot & 15;
  if (gsub & 2) qt = 15 - qt;          // complementary pairing on each CU
  const int g = gsub * 8 + xcd;        // (b,h) group 0..31
  const int h = g & 15;
  const int b = g >> 4;
  const int i0 = qt * 64;

  const int swz = ((t & 7) ^ ((t >> 3) & 7)) * 8;  // staging source-chunk swizzle
  const int c0 = (qd ^ (lr & 7)) * 8;              // fragment-read chunk offsets
  const int c1 = c0 ^ 32;
  const int row8 = t >> 3;

  const int jmax = min(K_, i0 + 64 + M_);

  // tiled pos fragment base: group for 64-key sub tt, frag pc is g0 + 4*tt + pc.
  const int g0 = 63 - (i0 >> 4) - w;
  const u16* pb0 = posT + (size_t)b * 147456 + qd * 128 + lr * 8;
  // fragment-tiled V base for this (b,h); per-lane fragment offsets
  const u16* vfb = vf + (size_t)(b * H_ + h) * 131072 + lr * 8;

  // ---- pre-loop staging: Q -> Ks[1][0]; phase0 K (both subs) -> buf0 ----
#pragma unroll
  for (int rd = 0; rd < 2; rd++)
    gll16(qb + (size_t)(b * S_ + i0 + rd * 32 + row8) * 1024 + h * 64 + swz,
          &Ks[1][0][0] + rd * 2048 + w * 512);
#pragma unroll
  for (int sb = 0; sb < 2; sb++)
#pragma unroll
    for (int rd = 0; rd < 2; rd++)
      gll16(kb + (size_t)(b * K_ + sb * 64 + rd * 32 + row8) * 1024 + h * 64 + swz,
            &Ks[0][sb][0] + rd * 2048 + w * 512);
  // preload pos fragments for phase0 subs (registers, coalesced)
  short8 pgA0[5], pgA1[5], pgB0[5], pgB1[5];
  {
    const u16* pp = pb0 + (size_t)g0 * 1024;
#pragma unroll
    for (int pc = 0; pc < 5; pc++) {
      pgA0[pc] = *(const short8*)(pp + pc * 1024);
      pgA1[pc] = *(const short8*)(pp + pc * 1024 + 512);
    }
    const u16* p2 = pb0 + (size_t)(g0 + 4) * 1024;
#pragma unroll
    for (int pc = 0; pc < 5; pc++) {
      pgB0[pc] = *(const short8*)(p2 + pc * 1024);
      pgB1[pc] = *(const short8*)(p2 + pc * 1024 + 512);
    }
  }
  __syncthreads();
  const short8 aQ0 = *(const short8*)&Ks[1][0][(w * 16 + lr) * 64 + c0];
  const short8 aQ1 = *(const short8*)&Ks[1][0][(w * 16 + lr) * 64 + c1];

  f32x4 accO[4];
#pragma unroll
  for (int d = 0; d < 4; d++) accO[d] = (f32x4){0.f, 0.f, 0.f, 0.f};
  float lsum[4];
#pragma unroll
  for (int r = 0; r < 4; r++) lsum[r] = 0.f;

  for (int j0 = 0, ph = 0; j0 < jmax; j0 += 128, ph++) {
    __syncthreads();
    const int cb = ph & 1;
    const int nb = cb ^ 1;
    const int j0n = j0 + 128;
    // ---- stage phase+1 K (per-sub guard; valid subs are fully in-bounds) ----
#pragma unroll
    for (int sb = 0; sb < 2; sb++)
      if (j0n + sb * 64 < jmax) {
#pragma unroll
        for (int rd = 0; rd < 2; rd++)
          gll16(kb + (size_t)(b * K_ + j0n + sb * 64 + rd * 32 + row8) * 1024 + h * 64 + swz,
                &Ks[nb][sb][0] + rd * 2048 + w * 512);
      }

    // ================= SUB 0 (keys j0 .. j0+63) =================
    {
      // V fragments direct from L2 (coalesced 1KB each); latency hides under QK+softmax
      const u16* vtp = vfb + (size_t)(j0 >> 6) * 4096;
      short8 vA[4], vB[4];
#pragma unroll
      for (int d2 = 0; d2 < 4; d2++) {
        vA[d2] = *(const short8*)(vtp + (d2 * 8 + qd) * 128);
        vB[d2] = *(const short8*)(vtp + (d2 * 8 + qd + 4) * 128);
      }
      __builtin_amdgcn_s_setprio(1);
      f32x4 zp[5];
#pragma unroll
      for (int pc = 0; pc < 5; pc++) {
        f32x4 z = {0.f, 0.f, 0.f, 0.f};
        z = mfma16(aQ0, pgA0[pc], z);
        zp[pc] = mfma16(aQ1, pgA1[pc], z);
      }
      f32x4 sqk[4];
#pragma unroll
      for (int kc = 0; kc < 4; kc++) {
        const short8 bK0 = *(const short8*)&Ks[cb][0][(kc * 16 + lr) * 64 + c0];
        const short8 bK1 = *(const short8*)&Ks[cb][0][(kc * 16 + lr) * 64 + c1];
        f32x4 z = {0.f, 0.f, 0.f, 0.f};
        z = mfma16(aQ0, bK0, z);
        sqk[kc] = mfma16(aQ1, bK1, z);
      }
      __builtin_amdgcn_s_setprio(0);
      // prefetch pgA for next phase's sub0 (tt = 2*ph+2)
      {
        const u16* pn = pb0 + (size_t)(g0 + 4 * (2 * ph + 2)) * 1024;
#pragma unroll
        for (int pc = 0; pc < 5; pc++) {
          pgA0[pc] = *(const short8*)(pn + pc * 1024);
          pgA1[pc] = *(const short8*)(pn + pc * 1024 + 512);
        }
      }
      // shuffle-based skew gather + max-free softmax
      const bool tail = (j0 + 63 > i0 + w * 16 + M_);
      float p[4][4];
#pragma unroll
      for (int r = 0; r < 4; r++) {
        const int iL = qd * 4 + r;
        const int d = 15 + lr - iL;
        const int srcl = qd * 16 + (d & 15);
        const bool hi = (d >> 4) & 1;
        float g0s = __shfl(zp[0][r], srcl, 64);
        float g1s = __shfl(zp[1][r], srcl, 64);
        float g2s = __shfl(zp[2][r], srcl, 64);
        float g3s = __shfl(zp[3][r], srcl, 64);
        float g4s = __shfl(zp[4][r], srcl, 64);
        float s0 = sqk[0][r] + (hi ? g1s : g0s);
        float s1 = sqk[1][r] + (hi ? g2s : g1s);
        float s2 = sqk[2][r] + (hi ? g3s : g2s);
        float s3 = sqk[3][r] + (hi ? g4s : g3s);
        if (tail) {
          const int key = j0 + lr, lim = i0 + w * 16 + iL + M_;
          if (key      > lim) s0 = NEG_BIG;
          if (key + 16 > lim) s1 = NEG_BIG;
          if (key + 32 > lim) s2 = NEG_BIG;
          if (key + 48 > lim) s3 = NEG_BIG;
        }
        p[0][r] = __expf(s0);
        p[1][r] = __expf(s1);
        p[2][r] = __expf(s2);
        p[3][r] = __expf(s3);
        lsum[r] += p[0][r] + p[1][r] + p[2][r] + p[3][r];
      }
      // P -> wave-private LDS (XOR chunk swizzle) -> A-fragments
#pragma unroll
      for (int r = 0; r < 4; r++) {
        const int row = qd * 4 + r;
        const int cbase = row * 64;
        const int rx = row & 7;
        const int lo = lr & 7, hi8 = lr >> 3;
#pragma unroll
        for (int kc = 0; kc < 4; kc++)
          Pt[w][cbase + ((((kc << 1) | hi8) ^ rx) << 3) + lo] = f2bf(p[kc][r]);
      }
      __asm__ volatile("s_waitcnt lgkmcnt(0)" ::: "memory");
      const short8 aP0 = *(const short8*)&Pt[w][lr * 64 + ((qd ^ (lr & 7)) << 3)];
      const short8 aP1 = *(const short8*)&Pt[w][lr * 64 + (((qd + 4) ^ (lr & 7)) << 3)];
      // P @ V (register fragments)
      __builtin_amdgcn_s_setprio(1);
#pragma unroll
      for (int d2 = 0; d2 < 4; d2++) {
        accO[d2] = mfma16(aP0, vA[d2], accO[d2]);
        accO[d2] = mfma16(aP1, vB[d2], accO[d2]);
      }
      __builtin_amdgcn_s_setprio(0);
    }

    // ================= SUB 1 (keys j0+64 .. j0+127) =================
    if (j0 + 64 < jmax) {
      const int j1 = j0 + 64;
      const u16* vtp = vfb + (size_t)(j1 >> 6) * 4096;
      short8 vA[4], vB[4];
#pragma unroll
      for (int d2 = 0; d2 < 4; d2++) {
        vA[d2] = *(const short8*)(vtp + (d2 * 8 + qd) * 128);
        vB[d2] = *(const short8*)(vtp + (d2 * 8 + qd + 4) * 128);
      }
      __builtin_amdgcn_s_setprio(1);
      f32x4 zp[5];
#pragma unroll
      for (int pc = 0; pc < 5; pc++) {
        f32x4 z = {0.f, 0.f, 0.f, 0.f};
        z = mfma16(aQ0, pgB0[pc], z);
        zp[pc] = mfma16(aQ1, pgB1[pc], z);
      }
      f32x4 sqk[4];
#pragma unroll
      for (int kc = 0; kc < 4; kc++) {
        const short8 bK0 = *(const short8*)&Ks[cb][1][(kc * 16 + lr) * 64 + c0];
        const short8 bK1 = *(const short8*)&Ks[cb][1][(kc * 16 + lr) * 64 + c1];
        f32x4 z = {0.f, 0.f, 0.f, 0.f};
        z = mfma16(aQ0, bK0, z);
        sqk[kc] = mfma16(aQ1, bK1, z);
      }
      __builtin_amdgcn_s_setprio(0);
      // prefetch pgB for next phase's sub1 (tt = 2*ph+3)
      {
        const u16* pn = pb0 + (size_t)(g0 + 4 * (2 * ph + 3)) * 1024;
#pragma unroll
        for (int pc = 0; pc < 5; pc++) {
          pgB0[pc] = *(const short8*)(pn + pc * 1024);
          pgB1[pc] = *(const short8*)(pn + pc * 1024 + 512);
        }
      }
      const bool tail = (j1 + 63 > i0 + w * 16 + M_);
      float p[4][4];
#pragma unroll
      for (int r = 0; r < 4; r++) {
        const int iL = qd * 4 + r;
        const int d = 15 + lr - iL;
        const int srcl = qd * 16 + (d & 15);
        const bool hi = (d >> 4) & 1;
        float g0s = __shfl(zp[0][r], srcl, 64);
        float g1s = __shfl(zp[1][r], srcl, 64);
        float g2s = __shfl(zp[2][r], srcl, 64);
        float g3s = __shfl(zp[3][r], srcl, 64);
        float g4s = __shfl(zp[4][r], srcl, 64);
        float s0 = sqk[0][r] + (hi ? g1s : g0s);
        float s1 = sqk[1][r] + (hi ? g2s : g1s);
        float s2 = sqk[2][r] + (hi ? g3s : g2s);
        float s3 = sqk[3][r] + (hi ? g4s : g3s);
        if (tail) {
          const int key = j1 + lr, lim = i0 + w * 16 + iL + M_;
          if (key      > lim) s0 = NEG_BIG;
          if (key + 16 > lim) s1 = NEG_BIG;
          if (key + 32 > lim) s2 = NEG_BIG;
          if (key + 48 > lim) s3 = NEG_BIG;
        }
        p[0][r] = __expf(s0);
        p[1][r] = __expf(s1);
        p[2][r] = __expf(s2);
        p[3][r] = __expf(s3);
        lsum[r] += p[0][r] + p[1][r] + p[2][r] + p[3][r];
      }
#pragma unroll
      for (int r = 0; r < 4; r++) {
        const int row = qd * 4 + r;
        const int cbase = row * 64;
        const int rx = row & 7;
        const int lo = lr & 7, hi8 = lr >> 3;
#pragma unroll
        for (int kc = 0; kc < 4; kc++)
          Pt[w][cbase + ((((kc << 1) | hi8) ^ rx) << 3) + lo] = f2bf(p[kc][r]);
      }
      __asm__ volatile("s_waitcnt lgkmcnt(0)" ::: "memory");
      const short8 aP0 = *(const short8*)&Pt[w][lr * 64 + ((qd ^ (lr & 7)) << 3)];
      const short8 aP1 = *(const short8*)&Pt[w][lr * 64 + (((qd + 4) ^ (lr & 7)) << 3)];
      __builtin_amdgcn_s_setprio(1);
#pragma unroll
      for (int d2 = 0; d2 < 4; d2++) {
        accO[d2] = mfma16(aP0, vA[d2], accO[d2]);
        accO[d2] = mfma16(aP1, vB[d2], accO[d2]);
      }
      __builtin_amdgcn_s_setprio(0);
    }
  }

  // ---- epilogue: one 16-lane reduction of lsum, then normalize ----
  float inv[4];
#pragma unroll
  for (int r = 0; r < 4; r++) {
#pragma unroll
    for (int msk = 1; msk < 16; msk <<= 1) lsum[r] += __shfl_xor(lsum[r], msk, 64);
    inv[r] = 1.0f / lsum[r];
  }
#pragma unroll
  for (int d2 = 0; d2 < 4; d2++)
#pragma unroll
    for (int r = 0; r < 4; r++) {
      const int iG = i0 + w * 16 + qd * 4 + r;
      ab[(size_t)(b * S_ + iG) * 1024 + h * 64 + d2 * 16 + lr] = f2bf(accO[d2][r] * inv[r]);
    }
}

// ---------------- launch ----------------
extern "C" void kernel_launch(void* const* d_in, const int* in_sizes, int n_in,
                              void* d_out, int out_size, void* d_ws, size_t ws_size,
                              hipStream_t stream) {
  const float* hidden = (const float*)d_in[0];
  const float* pos    = (const float*)d_in[1];
  const float* memory = (const float*)d_in[2];
  // d_in[3] = mask (bool) — causality applied analytically, unused
  const float* Wq = (const float*)d_in[4];
  const float* Wk = (const float*)d_in[5];
  const float* Wv = (const float*)d_in[6];
  const float* Wo = (const float*)d_in[7];
  const float* gamma = (const float*)d_in[8];
  const float* beta  = (const float*)d_in[9];

  char* ws = (char*)d_ws;
  u16* cln  = (u16*)(ws);               // 8 MB
  u16* qb   = (u16*)(ws + 8388608);     // 4 MB (pre-scaled 1/32)
  u16* kb   = (u16*)(ws + 12582912);    // 8 MB
  u16* vf   = (u16*)(ws + 20971520);    // 8 MB fragment-tiled V
  u16* ab   = (u16*)(ws + 29360128);    // 4 MB
  u16* WqT  = (u16*)(ws + 33554432);    // 4 x 2 MB contiguous (WqT|WkT|WvT|WoT)
  u16* WkT  = WqT + 1048576;
  u16* WvT  = WkT + 1048576;
  u16* WoT  = WvT + 1048576;
  u16* posT = (u16*)(ws + 41943040);    // 0.56 MB tiled pos (144-group stride)

  prep_kernel<<<dim3(5256), 256, 0, stream>>>(
      hidden, memory, gamma, beta, cln,
      Wq, Wk, Wv, Wo, WqT, WkT, WvT, WoT, pos, posT);
  gemm_qkv_kernel<<<dim3(24, 32), 256, 0, stream>>>(cln, WqT, qb, kb, vf);
  attn_kernel<<<dim3(S_ / 64, H_, B_), 256, 0, stream>>>(qb, kb, vf, posT, ab);
  out_gemm_kernel<<<dim3(16, 16), 256, 0, stream>>>(ab, WoT, cln, (float*)d_out);
}

// Round 13
// 191.050 us; speedup vs baseline: 1.0144x; 1.0144x over previous
//
#include <hip/hip_runtime.h>
#include <hip/hip_bf16.h>

// Problem constants (B,S,M,D,H,DH = 2,1024,1024,1024,16,64)
#define B_ 2
#define S_ 1024
#define M_ 1024
#define D_ 1024
#define H_ 16
#define DH_ 64
#define K_ 2048
#define R_ 4095

// finite stand-in for -inf (avoids inf arithmetic under fast-math)
#define NEG_BIG (-1e30f)

typedef unsigned short u16;
typedef short short8 __attribute__((ext_vector_type(8)));
typedef float f32x4 __attribute__((ext_vector_type(4)));

__device__ __forceinline__ u16 f2bf(float f) {
  __hip_bfloat16 h = __float2bfloat16(f);
  return *reinterpret_cast<u16*>(&h);
}
__device__ __forceinline__ float bf2f(u16 u) {
  __hip_bfloat16 h;
  *reinterpret_cast<u16*>(&h) = u;
  return __bfloat162float(h);
}

// async global->LDS, 16B per lane; LDS dest = wave-uniform base + lane*16
__device__ __forceinline__ void gll16(const void* g, const void* l) {
  __builtin_amdgcn_global_load_lds(
      (const __attribute__((address_space(1))) unsigned int*)g,
      (__attribute__((address_space(3))) unsigned int*)l, 16, 0, 0);
}

__device__ __forceinline__ f32x4 mfma16(short8 a, short8 b, f32x4 c) {
  return __builtin_amdgcn_mfma_f32_16x16x32_bf16(a, b, c, 0, 0, 0);
}

// ---------------- fused prep: LN(concat) + 4x weight transpose + pos tiled cvt ----------
// LN now per-WAVE (one row per 64-lane wave, 16 f32/lane): no LDS, no barrier,
// 6 shfl_xor rounds; 4 rows/block -> 1024 blocks (was 4096 + barrier each).
// posT layout: [b][g<144][oct<8][r<16][j<8] bf16 (136 groups written, 8 pad groups).
__global__ __launch_bounds__(256) void prep_kernel(
    const float* __restrict__ hidden, const float* __restrict__ memory,
    const float* __restrict__ gamma, const float* __restrict__ beta,
    u16* __restrict__ cln,
    const float* __restrict__ W0, const float* __restrict__ W1,
    const float* __restrict__ W2, const float* __restrict__ W3,
    u16* __restrict__ O0, u16* __restrict__ O1,
    u16* __restrict__ O2, u16* __restrict__ O3,
    const float* __restrict__ pos, u16* __restrict__ posT) {
  __shared__ u16 tile[64][66];
  const int bx = blockIdx.x;
  const int t = threadIdx.x;

  if (bx < 1024) {  // LayerNorm: 4 rows/block, one per wave
    const int row = bx * 4 + (t >> 6);
    const int lane = t & 63;
    const int b = row >> 11;
    const int idx = row & (K_ - 1);
    const float* src = (idx < M_)
        ? memory + (size_t)(b * M_ + idx) * D_
        : hidden + (size_t)(b * S_ + (idx - M_)) * D_;
    float4 rv[4];
    float s = 0.f, ss = 0.f;
#pragma unroll
    for (int k = 0; k < 4; k++) {
      rv[k] = ((const float4*)src)[k * 64 + lane];
      s += rv[k].x + rv[k].y + rv[k].z + rv[k].w;
      ss += rv[k].x * rv[k].x + rv[k].y * rv[k].y + rv[k].z * rv[k].z + rv[k].w * rv[k].w;
    }
#pragma unroll
    for (int m = 1; m < 64; m <<= 1) {
      s += __shfl_xor(s, m, 64);
      ss += __shfl_xor(ss, m, 64);
    }
    const float mu = s * (1.0f / D_);
    const float var = ss * (1.0f / D_) - mu * mu;
    const float rstd = rsqrtf(var + 1e-5f);
    u16* drow = cln + (size_t)row * D_;
#pragma unroll
    for (int k = 0; k < 4; k++) {
      const float4 gv = ((const float4*)gamma)[k * 64 + lane];
      const float4 bv = ((const float4*)beta)[k * 64 + lane];
      ushort4 ov;
      ov.x = f2bf((rv[k].x - mu) * rstd * gv.x + bv.x);
      ov.y = f2bf((rv[k].y - mu) * rstd * gv.y + bv.y);
      ov.z = f2bf((rv[k].z - mu) * rstd * gv.z + bv.z);
      ov.w = f2bf((rv[k].w - mu) * rstd * gv.w + bv.w);
      ((ushort4*)drow)[k * 64 + lane] = ov;
    }
    return;
  }
  if (bx < 2048) {  // weight transpose slab (float4-vectorized)
    const int z = (bx - 1024) >> 8;
    const int rem = (bx - 1024) & 255;
    const float* in; u16* out;
    switch (z) {
      case 0:  in = W0; out = O0; break;
      case 1:  in = W1; out = O1; break;
      case 2:  in = W2; out = O2; break;
      default: in = W3; out = O3; break;
    }
    const int k0 = (rem & 15) * 64, n0 = (rem >> 4) * 64;
    const int c4 = t & 15, rr = t >> 4;     // 16 float4-cols x 16 rows per pass
#pragma unroll
    for (int p = 0; p < 4; p++) {
      const int i = rr + p * 16;
      float4 v = *(const float4*)&in[(size_t)(k0 + i) * D_ + n0 + c4 * 4];
      tile[i][c4 * 4 + 0] = f2bf(v.x);
      tile[i][c4 * 4 + 1] = f2bf(v.y);
      tile[i][c4 * 4 + 2] = f2bf(v.z);
      tile[i][c4 * 4 + 3] = f2bf(v.w);
    }
    __syncthreads();
#pragma unroll
    for (int p = 0; p < 4; p++) {
      const int i = rr + p * 16;
      ushort4 o;
      o.x = tile[c4 * 4 + 0][i];
      o.y = tile[c4 * 4 + 1][i];
      o.z = tile[c4 * 4 + 2][i];
      o.w = tile[c4 * 4 + 3][i];
      *(ushort4*)&out[(size_t)(n0 + i) * D_ + k0 + c4 * 4] = o;
    }
    return;
  }
  // pos f32 -> bf16, tiled: u enumerates (b, g, r, oct); 136 groups of 16 rows per batch
  {
    const int u = (bx - 2048) * 256 + t;    // [0, 34816)
    const int oct = u & 7;
    const int r = (u >> 3) & 15;
    const int g = (u >> 7) % 136;
    const int b = u / 17408;                // 136*128
    const int row = g * 16 + r;             // <= 2175 < R_ (always in-bounds)
    const float* s = pos + ((size_t)b * R_ + row) * 64 + oct * 8;
    float4 v0 = ((const float4*)s)[0];
    float4 v1 = ((const float4*)s)[1];
    ushort4 oA, oB;
    oA.x = f2bf(v0.x); oA.y = f2bf(v0.y); oA.z = f2bf(v0.z); oA.w = f2bf(v0.w);
    oB.x = f2bf(v1.x); oB.y = f2bf(v1.y); oB.z = f2bf(v1.z); oB.w = f2bf(v1.w);
    u16* d = posT + (size_t)(b * 144 + g) * 1024 + oct * 128 + r * 8;  // 144-group stride
    ((ushort4*)d)[0] = oA;
    ((ushort4*)d)[1] = oB;
  }
}

// row r of the "hidden slice" view -> row of c_ln
__device__ __forceinline__ int maprow_hidden(int r) {
  return r + ((r >> 10) << 10) + M_;
}

// ---------------- QKV GEMM: BK=64, XOR-swizzled staging, 3 blocks/CU ----------------
// LDS-staged coalesced epilogue (R11-proven). V written in FRAGMENT-TILED layout
// vf[bh][kt<32][d2<4][ch<8][lr<16][8] (R12-proven).
__global__ __launch_bounds__(256, 3) void gemm_qkv_kernel(
    const u16* __restrict__ A, const u16* __restrict__ Bt,
    u16* __restrict__ qb, u16* __restrict__ kb, u16* __restrict__ vf) {
  __shared__ __align__(16) u16 shm[128 * 132];   // 33 KB: As|Bs during loop, C-tile after
  u16* As = shm;                 // 128*64
  u16* Bs = shm + 8192;          // 128*64
  const int t = threadIdx.x;
  const int lane = t & 63, w = t >> 6;
  const int wm = w >> 1, wn = w & 1;
  const int qd = lane >> 4, lr = lane & 15;
  const int m0 = blockIdx.y * 128, n0 = blockIdx.x * 128;
  if (n0 < 1024 && !(m0 & 1024)) return;   // dead Q tiles (memory rows)

  const int swz = ((t & 7) ^ ((t >> 3) & 7)) * 8;  // source-chunk swizzle
  const int c0 = (qd ^ (lr & 7)) * 8;
  const int c1 = c0 ^ 32;
  const int row8 = (t >> 3) & 7;

  f32x4 acc[4][4];
#pragma unroll
  for (int mt = 0; mt < 4; mt++)
#pragma unroll
    for (int nt = 0; nt < 4; nt++) acc[mt][nt] = (f32x4){0.f, 0.f, 0.f, 0.f};

  for (int kt = 0; kt < 1024; kt += 64) {
#pragma unroll
    for (int p = 0; p < 4; p++) {
      const int ra = w * 32 + p * 8 + row8;
      gll16(A + (size_t)(m0 + ra) * 1024 + kt + swz, As + (w * 32 + p * 8) * 64);
      gll16(Bt + (size_t)(n0 + ra) * 1024 + kt + swz, Bs + (w * 32 + p * 8) * 64);
    }
    __syncthreads();
    short8 a0[4], a1[4], b0[4], b1[4];
#pragma unroll
    for (int mt = 0; mt < 4; mt++) {
      a0[mt] = *(const short8*)&As[(wm * 64 + mt * 16 + lr) * 64 + c0];
      a1[mt] = *(const short8*)&As[(wm * 64 + mt * 16 + lr) * 64 + c1];
    }
#pragma unroll
    for (int nt = 0; nt < 4; nt++) {
      b0[nt] = *(const short8*)&Bs[(wn * 64 + nt * 16 + lr) * 64 + c0];
      b1[nt] = *(const short8*)&Bs[(wn * 64 + nt * 16 + lr) * 64 + c1];
    }
#pragma unroll
    for (int mt = 0; mt < 4; mt++)
#pragma unroll
      for (int nt = 0; nt < 4; nt++) {
        acc[mt][nt] = mfma16(a0[mt], b0[nt], acc[mt][nt]);
        acc[mt][nt] = mfma16(a1[mt], b1[nt], acc[mt][nt]);
      }
    __syncthreads();
  }

  // ---- epilogue: stage C-tile (or C^T for V) into LDS, then coalesced stores ----
  const bool isV = (n0 >= 2048);
  if (!isV) {                    // Q (scaled) or K: row-major [row][col], pad 132
    const float sc = (n0 < 1024) ? 0.03125f : 1.0f;
#pragma unroll
    for (int mt = 0; mt < 4; mt++)
#pragma unroll
      for (int nt = 0; nt < 4; nt++) {
        const int row0 = wm * 64 + mt * 16 + qd * 4;
        const int col = wn * 64 + nt * 16 + lr;
#pragma unroll
        for (int r = 0; r < 4; r++)
          shm[(row0 + r) * 132 + col] = f2bf(acc[mt][nt][r] * sc);
      }
  } else {                       // V: transposed [nn][kk], ushort4 along kk
#pragma unroll
    for (int mt = 0; mt < 4; mt++)
#pragma unroll
      for (int nt = 0; nt < 4; nt++) {
        const int kk0 = wm * 64 + mt * 16 + qd * 4;
        const int nn = wn * 64 + nt * 16 + lr;
        ushort4 pk;
        pk.x = f2bf(acc[mt][nt][0]);
        pk.y = f2bf(acc[mt][nt][1]);
        pk.z = f2bf(acc[mt][nt][2]);
        pk.w = f2bf(acc[mt][nt][3]);
        *(ushort4*)&shm[nn * 132 + kk0] = pk;
      }
  }
  __syncthreads();
  // 2048 16B-chunks (128 rows x 16), 8 per thread; consecutive t -> contiguous runs
  const int bq = m0 >> 11;
#pragma unroll
  for (int i = 0; i < 8; i++) {
    const int flat = i * 256 + t;
    const int row = flat >> 4;
    const int ch = flat & 15;
    const ushort4 v0 = *(const ushort4*)&shm[row * 132 + ch * 8];
    const ushort4 v1 = *(const ushort4*)&shm[row * 132 + ch * 8 + 4];
    u16* dst;
    if (n0 < 1024) {
      const int qrow = (bq << 10) | ((m0 + row) & 1023);
      dst = qb + (size_t)qrow * 1024 + n0 + ch * 8;
    } else if (!isV) {
      const int key = (m0 + row) & (K_ - 1);
      dst = kb + (size_t)(bq * K_ + key) * 1024 + (n0 - 1024) + ch * 8;
    } else {
      // fragment-tiled vf: row = dh within 128-col block, chunk = 8 keys
      const int dhg = (n0 - 2048) + row;           // h*64 + dh within batch
      const int bh = (bq << 4) | (dhg >> 6);
      const int dh = dhg & 63;
      const int gk = (m0 & (K_ - 1)) + ch * 8;     // global key of this chunk
      const int ktile = gk >> 6;
      const int w6ch = (gk & 63) >> 3;
      const int d2 = dh >> 4, lrr = dh & 15;
      dst = vf + (size_t)bh * 131072 + (size_t)ktile * 4096
               + ((d2 * 8 + w6ch) * 16 + lrr) * 8;
    }
    short8 vv;
    *(ushort4*)&vv = v0;
    *(((ushort4*)&vv) + 1) = v1;
    *(short8*)dst = vv;          // one 16B store
  }
}

// ---------------- out GEMM: 64x64 tiles (512 blocks -> 2 blocks/CU, 8 waves/CU), ------
// BK=64, XOR-swizzled (qkv's proven pattern). Was 128x64 at 256 blocks = 1/CU
// latency-bound. acc[2][2], 8 MFMA/wave/step. LDS 16 KB.
__global__ __launch_bounds__(256, 2) void out_gemm_kernel(
    const u16* __restrict__ A, const u16* __restrict__ Bt,
    const u16* __restrict__ resid, float* __restrict__ Cf) {
  __shared__ __align__(16) u16 As[64 * 64];    // 8 KB
  __shared__ __align__(16) u16 Bs[64 * 64];    // 8 KB
  const int t = threadIdx.x;
  const int lane = t & 63, w = t >> 6;
  const int wm = w >> 1, wn = w & 1;
  const int qd = lane >> 4, lr = lane & 15;
  const int m0 = blockIdx.y * 64, n0 = blockIdx.x * 64;

  const int swz = ((t & 7) ^ ((t >> 3) & 7)) * 8;  // source-chunk swizzle
  const int c0 = (qd ^ (lr & 7)) * 8;              // fragment-read chunk offsets
  const int c1 = c0 ^ 32;
  const int row8 = (t >> 3) & 7;

  f32x4 acc[2][2];
#pragma unroll
  for (int mt = 0; mt < 2; mt++)
#pragma unroll
    for (int nt = 0; nt < 2; nt++) acc[mt][nt] = (f32x4){0.f, 0.f, 0.f, 0.f};

  for (int kt = 0; kt < 1024; kt += 64) {
#pragma unroll
    for (int p = 0; p < 2; p++) {
      const int ra = w * 16 + p * 8 + row8;
      gll16(A + (size_t)(m0 + ra) * 1024 + kt + swz, As + (w * 16 + p * 8) * 64);
      gll16(Bt + (size_t)(n0 + ra) * 1024 + kt + swz, Bs + (w * 16 + p * 8) * 64);
    }
    __syncthreads();
    short8 a0[2], a1[2], b0[2], b1[2];
#pragma unroll
    for (int mt = 0; mt < 2; mt++) {
      a0[mt] = *(const short8*)&As[(wm * 32 + mt * 16 + lr) * 64 + c0];
      a1[mt] = *(const short8*)&As[(wm * 32 + mt * 16 + lr) * 64 + c1];
    }
#pragma unroll
    for (int nt = 0; nt < 2; nt++) {
      b0[nt] = *(const short8*)&Bs[(wn * 32 + nt * 16 + lr) * 64 + c0];
      b1[nt] = *(const short8*)&Bs[(wn * 32 + nt * 16 + lr) * 64 + c1];
    }
#pragma unroll
    for (int mt = 0; mt < 2; mt++)
#pragma unroll
      for (int nt = 0; nt < 2; nt++) {
        acc[mt][nt] = mfma16(a0[mt], b0[nt], acc[mt][nt]);
        acc[mt][nt] = mfma16(a1[mt], b1[nt], acc[mt][nt]);
      }
    __syncthreads();
  }

#pragma unroll
  for (int mt = 0; mt < 2; mt++)
#pragma unroll
    for (int nt = 0; nt < 2; nt++)
#pragma unroll
      for (int r = 0; r < 4; r++) {
        const int row = m0 + wm * 32 + mt * 16 + qd * 4 + r;
        const int col = n0 + wn * 32 + nt * 16 + lr;
        float v = acc[mt][nt][r] + bf2f(resid[(size_t)maprow_hidden(row) * 1024 + col]);
        Cf[(size_t)row * 1024 + col] = v;
      }
}

// ---------------- attention: KVBLK=128, V DIRECT FROM L2 (no LDS staging) --------------
// R12-proven; byte-identical. grid (16, H, B).
__global__ __launch_bounds__(256, 2) void attn_kernel(
    const u16* __restrict__ qb, const u16* __restrict__ kb,
    const u16* __restrict__ vf, const u16* __restrict__ posT,
    u16* __restrict__ ab) {
  __shared__ __align__(16) u16 Ks[2][2][64 * 64];   // 32 KB (Ks[1][0] aliases Q pre-loop)
  __shared__ __align__(16) u16 Pt[4][16 * 64];      // 8 KB wave-private (XOR-swizzled)

  const int t = threadIdx.x;
  const int lane = t & 63, w = t >> 6;
  const int qd = lane >> 4, lr = lane & 15;

  // XCD-grouping remap (bijective on 512 blocks) — R4-proven
  const int flat = blockIdx.x + 16 * blockIdx.y + 256 * blockIdx.z;
  const int xcd = flat & 7;
  const int slot = flat >> 3;          // 0..63 within XCD
  const int gsub = slot >> 4;          // 0..3
  int qt = slot & 15;
  if (gsub & 2) qt = 15 - qt;          // complementary pairing on each CU
  const int g = gsub * 8 + xcd;        // (b,h) group 0..31
  const int h = g & 15;
  const int b = g >> 4;
  const int i0 = qt * 64;

  const int swz = ((t & 7) ^ ((t >> 3) & 7)) * 8;  // staging source-chunk swizzle
  const int c0 = (qd ^ (lr & 7)) * 8;              // fragment-read chunk offsets
  const int c1 = c0 ^ 32;
  const int row8 = t >> 3;

  const int jmax = min(K_, i0 + 64 + M_);

  // tiled pos fragment base: group for 64-key sub tt, frag pc is g0 + 4*tt + pc.
  const int g0 = 63 - (i0 >> 4) - w;
  const u16* pb0 = posT + (size_t)b * 147456 + qd * 128 + lr * 8;
  // fragment-tiled V base for this (b,h); per-lane fragment offsets
  const u16* vfb = vf + (size_t)(b * H_ + h) * 131072 + lr * 8;

  // ---- pre-loop staging: Q -> Ks[1][0]; phase0 K (both subs) -> buf0 ----
#pragma unroll
  for (int rd = 0; rd < 2; rd++)
    gll16(qb + (size_t)(b * S_ + i0 + rd * 32 + row8) * 1024 + h * 64 + swz,
          &Ks[1][0][0] + rd * 2048 + w * 512);
#pragma unroll
  for (int sb = 0; sb < 2; sb++)
#pragma unroll
    for (int rd = 0; rd < 2; rd++)
      gll16(kb + (size_t)(b * K_ + sb * 64 + rd * 32 + row8) * 1024 + h * 64 + swz,
            &Ks[0][sb][0] + rd * 2048 + w * 512);
  // preload pos fragments for phase0 subs (registers, coalesced)
  short8 pgA0[5], pgA1[5], pgB0[5], pgB1[5];
  {
    const u16* pp = pb0 + (size_t)g0 * 1024;
#pragma unroll
    for (int pc = 0; pc < 5; pc++) {
      pgA0[pc] = *(const short8*)(pp + pc * 1024);
      pgA1[pc] = *(const short8*)(pp + pc * 1024 + 512);
    }
    const u16* p2 = pb0 + (size_t)(g0 + 4) * 1024;
#pragma unroll
    for (int pc = 0; pc < 5; pc++) {
      pgB0[pc] = *(const short8*)(p2 + pc * 1024);
      pgB1[pc] = *(const short8*)(p2 + pc * 1024 + 512);
    }
  }
  __syncthreads();
  const short8 aQ0 = *(const short8*)&Ks[1][0][(w * 16 + lr) * 64 + c0];
  const short8 aQ1 = *(const short8*)&Ks[1][0][(w * 16 + lr) * 64 + c1];

  f32x4 accO[4];
#pragma unroll
  for (int d = 0; d < 4; d++) accO[d] = (f32x4){0.f, 0.f, 0.f, 0.f};
  float lsum[4];
#pragma unroll
  for (int r = 0; r < 4; r++) lsum[r] = 0.f;

  for (int j0 = 0, ph = 0; j0 < jmax; j0 += 128, ph++) {
    __syncthreads();
    const int cb = ph & 1;
    const int nb = cb ^ 1;
    const int j0n = j0 + 128;
    // ---- stage phase+1 K (per-sub guard; valid subs are fully in-bounds) ----
#pragma unroll
    for (int sb = 0; sb < 2; sb++)
      if (j0n + sb * 64 < jmax) {
#pragma unroll
        for (int rd = 0; rd < 2; rd++)
          gll16(kb + (size_t)(b * K_ + j0n + sb * 64 + rd * 32 + row8) * 1024 + h * 64 + swz,
                &Ks[nb][sb][0] + rd * 2048 + w * 512);
      }

    // ================= SUB 0 (keys j0 .. j0+63) =================
    {
      // V fragments direct from L2 (coalesced 1KB each); latency hides under QK+softmax
      const u16* vtp = vfb + (size_t)(j0 >> 6) * 4096;
      short8 vA[4], vB[4];
#pragma unroll
      for (int d2 = 0; d2 < 4; d2++) {
        vA[d2] = *(const short8*)(vtp + (d2 * 8 + qd) * 128);
        vB[d2] = *(const short8*)(vtp + (d2 * 8 + qd + 4) * 128);
      }
      __builtin_amdgcn_s_setprio(1);
      f32x4 zp[5];
#pragma unroll
      for (int pc = 0; pc < 5; pc++) {
        f32x4 z = {0.f, 0.f, 0.f, 0.f};
        z = mfma16(aQ0, pgA0[pc], z);
        zp[pc] = mfma16(aQ1, pgA1[pc], z);
      }
      f32x4 sqk[4];
#pragma unroll
      for (int kc = 0; kc < 4; kc++) {
        const short8 bK0 = *(const short8*)&Ks[cb][0][(kc * 16 + lr) * 64 + c0];
        const short8 bK1 = *(const short8*)&Ks[cb][0][(kc * 16 + lr) * 64 + c1];
        f32x4 z = {0.f, 0.f, 0.f, 0.f};
        z = mfma16(aQ0, bK0, z);
        sqk[kc] = mfma16(aQ1, bK1, z);
      }
      __builtin_amdgcn_s_setprio(0);
      // prefetch pgA for next phase's sub0 (tt = 2*ph+2)
      {
        const u16* pn = pb0 + (size_t)(g0 + 4 * (2 * ph + 2)) * 1024;
#pragma unroll
        for (int pc = 0; pc < 5; pc++) {
          pgA0[pc] = *(const short8*)(pn + pc * 1024);
          pgA1[pc] = *(const short8*)(pn + pc * 1024 + 512);
        }
      }
      // shuffle-based skew gather + max-free softmax
      const bool tail = (j0 + 63 > i0 + w * 16 + M_);
      float p[4][4];
#pragma unroll
      for (int r = 0; r < 4; r++) {
        const int iL = qd * 4 + r;
        const int d = 15 + lr - iL;
        const int srcl = qd * 16 + (d & 15);
        const bool hi = (d >> 4) & 1;
        float g0s = __shfl(zp[0][r], srcl, 64);
        float g1s = __shfl(zp[1][r], srcl, 64);
        float g2s = __shfl(zp[2][r], srcl, 64);
        float g3s = __shfl(zp[3][r], srcl, 64);
        float g4s = __shfl(zp[4][r], srcl, 64);
        float s0 = sqk[0][r] + (hi ? g1s : g0s);
        float s1 = sqk[1][r] + (hi ? g2s : g1s);
        float s2 = sqk[2][r] + (hi ? g3s : g2s);
        float s3 = sqk[3][r] + (hi ? g4s : g3s);
        if (tail) {
          const int key = j0 + lr, lim = i0 + w * 16 + iL + M_;
          if (key      > lim) s0 = NEG_BIG;
          if (key + 16 > lim) s1 = NEG_BIG;
          if (key + 32 > lim) s2 = NEG_BIG;
          if (key + 48 > lim) s3 = NEG_BIG;
        }
        p[0][r] = __expf(s0);
        p[1][r] = __expf(s1);
        p[2][r] = __expf(s2);
        p[3][r] = __expf(s3);
        lsum[r] += p[0][r] + p[1][r] + p[2][r] + p[3][r];
      }
      // P -> wave-private LDS (XOR chunk swizzle) -> A-fragments
#pragma unroll
      for (int r = 0; r < 4; r++) {
        const int row = qd * 4 + r;
        const int cbase = row * 64;
        const int rx = row & 7;
        const int lo = lr & 7, hi8 = lr >> 3;
#pragma unroll
        for (int kc = 0; kc < 4; kc++)
          Pt[w][cbase + ((((kc << 1) | hi8) ^ rx) << 3) + lo] = f2bf(p[kc][r]);
      }
      __asm__ volatile("s_waitcnt lgkmcnt(0)" ::: "memory");
      const short8 aP0 = *(const short8*)&Pt[w][lr * 64 + ((qd ^ (lr & 7)) << 3)];
      const short8 aP1 = *(const short8*)&Pt[w][lr * 64 + (((qd + 4) ^ (lr & 7)) << 3)];
      // P @ V (register fragments)
      __builtin_amdgcn_s_setprio(1);
#pragma unroll
      for (int d2 = 0; d2 < 4; d2++) {
        accO[d2] = mfma16(aP0, vA[d2], accO[d2]);
        accO[d2] = mfma16(aP1, vB[d2], accO[d2]);
      }
      __builtin_amdgcn_s_setprio(0);
    }

    // ================= SUB 1 (keys j0+64 .. j0+127) =================
    if (j0 + 64 < jmax) {
      const int j1 = j0 + 64;
      const u16* vtp = vfb + (size_t)(j1 >> 6) * 4096;
      short8 vA[4], vB[4];
#pragma unroll
      for (int d2 = 0; d2 < 4; d2++) {
        vA[d2] = *(const short8*)(vtp + (d2 * 8 + qd) * 128);
        vB[d2] = *(const short8*)(vtp + (d2 * 8 + qd + 4) * 128);
      }
      __builtin_amdgcn_s_setprio(1);
      f32x4 zp[5];
#pragma unroll
      for (int pc = 0; pc < 5; pc++) {
        f32x4 z = {0.f, 0.f, 0.f, 0.f};
        z = mfma16(aQ0, pgB0[pc], z);
        zp[pc] = mfma16(aQ1, pgB1[pc], z);
      }
      f32x4 sqk[4];
#pragma unroll
      for (int kc = 0; kc < 4; kc++) {
        const short8 bK0 = *(const short8*)&Ks[cb][1][(kc * 16 + lr) * 64 + c0];
        const short8 bK1 = *(const short8*)&Ks[cb][1][(kc * 16 + lr) * 64 + c1];
        f32x4 z = {0.f, 0.f, 0.f, 0.f};
        z = mfma16(aQ0, bK0, z);
        sqk[kc] = mfma16(aQ1, bK1, z);
      }
      __builtin_amdgcn_s_setprio(0);
      // prefetch pgB for next phase's sub1 (tt = 2*ph+3)
      {
        const u16* pn = pb0 + (size_t)(g0 + 4 * (2 * ph + 3)) * 1024;
#pragma unroll
        for (int pc = 0; pc < 5; pc++) {
          pgB0[pc] = *(const short8*)(pn + pc * 1024);
          pgB1[pc] = *(const short8*)(pn + pc * 1024 + 512);
        }
      }
      const bool tail = (j1 + 63 > i0 + w * 16 + M_);
      float p[4][4];
#pragma unroll
      for (int r = 0; r < 4; r++) {
        const int iL = qd * 4 + r;
        const int d = 15 + lr - iL;
        const int srcl = qd * 16 + (d & 15);
        const bool hi = (d >> 4) & 1;
        float g0s = __shfl(zp[0][r], srcl, 64);
        float g1s = __shfl(zp[1][r], srcl, 64);
        float g2s = __shfl(zp[2][r], srcl, 64);
        float g3s = __shfl(zp[3][r], srcl, 64);
        float g4s = __shfl(zp[4][r], srcl, 64);
        float s0 = sqk[0][r] + (hi ? g1s : g0s);
        float s1 = sqk[1][r] + (hi ? g2s : g1s);
        float s2 = sqk[2][r] + (hi ? g3s : g2s);
        float s3 = sqk[3][r] + (hi ? g4s : g3s);
        if (tail) {
          const int key = j1 + lr, lim = i0 + w * 16 + iL + M_;
          if (key      > lim) s0 = NEG_BIG;
          if (key + 16 > lim) s1 = NEG_BIG;
          if (key + 32 > lim) s2 = NEG_BIG;
          if (key + 48 > lim) s3 = NEG_BIG;
        }
        p[0][r] = __expf(s0);
        p[1][r] = __expf(s1);
        p[2][r] = __expf(s2);
        p[3][r] = __expf(s3);
        lsum[r] += p[0][r] + p[1][r] + p[2][r] + p[3][r];
      }
#pragma unroll
      for (int r = 0; r < 4; r++) {
        const int row = qd * 4 + r;
        const int cbase = row * 64;
        const int rx = row & 7;
        const int lo = lr & 7, hi8 = lr >> 3;
#pragma unroll
        for (int kc = 0; kc < 4; kc++)
          Pt[w][cbase + ((((kc << 1) | hi8) ^ rx) << 3) + lo] = f2bf(p[kc][r]);
      }
      __asm__ volatile("s_waitcnt lgkmcnt(0)" ::: "memory");
      const short8 aP0 = *(const short8*)&Pt[w][lr * 64 + ((qd ^ (lr & 7)) << 3)];
      const short8 aP1 = *(const short8*)&Pt[w][lr * 64 + (((qd + 4) ^ (lr & 7)) << 3)];
      __builtin_amdgcn_s_setprio(1);
#pragma unroll
      for (int d2 = 0; d2 < 4; d2++) {
        accO[d2] = mfma16(aP0, vA[d2], accO[d2]);
        accO[d2] = mfma16(aP1, vB[d2], accO[d2]);
      }
      __builtin_amdgcn_s_setprio(0);
    }
  }

  // ---- epilogue: one 16-lane reduction of lsum, then normalize ----
  float inv[4];
#pragma unroll
  for (int r = 0; r < 4; r++) {
#pragma unroll
    for (int msk = 1; msk < 16; msk <<= 1) lsum[r] += __shfl_xor(lsum[r], msk, 64);
    inv[r] = 1.0f / lsum[r];
  }
#pragma unroll
  for (int d2 = 0; d2 < 4; d2++)
#pragma unroll
    for (int r = 0; r < 4; r++) {
      const int iG = i0 + w * 16 + qd * 4 + r;
      ab[(size_t)(b * S_ + iG) * 1024 + h * 64 + d2 * 16 + lr] = f2bf(accO[d2][r] * inv[r]);
    }
}

// ---------------- launch ----------------
extern "C" void kernel_launch(void* const* d_in, const int* in_sizes, int n_in,
                              void* d_out, int out_size, void* d_ws, size_t ws_size,
                              hipStream_t stream) {
  const float* hidden = (const float*)d_in[0];
  const float* pos    = (const float*)d_in[1];
  const float* memory = (const float*)d_in[2];
  // d_in[3] = mask (bool) — causality applied analytically, unused
  const float* Wq = (const float*)d_in[4];
  const float* Wk = (const float*)d_in[5];
  const float* Wv = (const float*)d_in[6];
  const float* Wo = (const float*)d_in[7];
  const float* gamma = (const float*)d_in[8];
  const float* beta  = (const float*)d_in[9];

  char* ws = (char*)d_ws;
  u16* cln  = (u16*)(ws);               // 8 MB
  u16* qb   = (u16*)(ws + 8388608);     // 4 MB (pre-scaled 1/32)
  u16* kb   = (u16*)(ws + 12582912);    // 8 MB
  u16* vf   = (u16*)(ws + 20971520);    // 8 MB fragment-tiled V
  u16* ab   = (u16*)(ws + 29360128);    // 4 MB
  u16* WqT  = (u16*)(ws + 33554432);    // 4 x 2 MB contiguous (WqT|WkT|WvT|WoT)
  u16* WkT  = WqT + 1048576;
  u16* WvT  = WkT + 1048576;
  u16* WoT  = WvT + 1048576;
  u16* posT = (u16*)(ws + 41943040);    // 0.56 MB tiled pos (144-group stride)

  prep_kernel<<<dim3(2184), 256, 0, stream>>>(
      hidden, memory, gamma, beta, cln,
      Wq, Wk, Wv, Wo, WqT, WkT, WvT, WoT, pos, posT);
  gemm_qkv_kernel<<<dim3(24, 32), 256, 0, stream>>>(cln, WqT, qb, kb, vf);
  attn_kernel<<<dim3(S_ / 64, H_, B_), 256, 0, stream>>>(qb, kb, vf, posT, ab);
  out_gemm_kernel<<<dim3(16, 32), 256, 0, stream>>>(ab, WoT, cln, (float*)d_out);
}

// Round 14
// 188.316 us; speedup vs baseline: 1.0292x; 1.0145x over previous
//
#include <hip/hip_runtime.h>
#include <hip/hip_bf16.h>

// Problem constants (B,S,M,D,H,DH = 2,1024,1024,1024,16,64)
#define B_ 2
#define S_ 1024
#define M_ 1024
#define D_ 1024
#define H_ 16
#define DH_ 64
#define K_ 2048
#define R_ 4095

// finite stand-in for -inf (avoids inf arithmetic under fast-math)
#define NEG_BIG (-1e30f)

typedef unsigned short u16;
typedef short short8 __attribute__((ext_vector_type(8)));
typedef float f32x4 __attribute__((ext_vector_type(4)));

__device__ __forceinline__ u16 f2bf(float f) {
  __hip_bfloat16 h = __float2bfloat16(f);
  return *reinterpret_cast<u16*>(&h);
}
__device__ __forceinline__ float bf2f(u16 u) {
  __hip_bfloat16 h;
  *reinterpret_cast<u16*>(&h) = u;
  return __bfloat162float(h);
}

// async global->LDS, 16B per lane; LDS dest = wave-uniform base + lane*16
__device__ __forceinline__ void gll16(const void* g, const void* l) {
  __builtin_amdgcn_global_load_lds(
      (const __attribute__((address_space(1))) unsigned int*)g,
      (__attribute__((address_space(3))) unsigned int*)l, 16, 0, 0);
}

__device__ __forceinline__ f32x4 mfma16(short8 a, short8 b, f32x4 c) {
  return __builtin_amdgcn_mfma_f32_16x16x32_bf16(a, b, c, 0, 0, 0);
}

// ---------------- fused prep: LN(concat) + 4x weight transpose + pos tiled cvt ----------
// LN per-WAVE (R13): one row per 64-lane wave, no LDS, no barrier.
// posT layout: [b][g<144][oct<8][r<16][j<8] bf16 (136 groups written, 8 pad groups).
__global__ __launch_bounds__(256) void prep_kernel(
    const float* __restrict__ hidden, const float* __restrict__ memory,
    const float* __restrict__ gamma, const float* __restrict__ beta,
    u16* __restrict__ cln,
    const float* __restrict__ W0, const float* __restrict__ W1,
    const float* __restrict__ W2, const float* __restrict__ W3,
    u16* __restrict__ O0, u16* __restrict__ O1,
    u16* __restrict__ O2, u16* __restrict__ O3,
    const float* __restrict__ pos, u16* __restrict__ posT) {
  __shared__ u16 tile[64][66];
  const int bx = blockIdx.x;
  const int t = threadIdx.x;

  if (bx < 1024) {  // LayerNorm: 4 rows/block, one per wave
    const int row = bx * 4 + (t >> 6);
    const int lane = t & 63;
    const int b = row >> 11;
    const int idx = row & (K_ - 1);
    const float* src = (idx < M_)
        ? memory + (size_t)(b * M_ + idx) * D_
        : hidden + (size_t)(b * S_ + (idx - M_)) * D_;
    float4 rv[4];
    float s = 0.f, ss = 0.f;
#pragma unroll
    for (int k = 0; k < 4; k++) {
      rv[k] = ((const float4*)src)[k * 64 + lane];
      s += rv[k].x + rv[k].y + rv[k].z + rv[k].w;
      ss += rv[k].x * rv[k].x + rv[k].y * rv[k].y + rv[k].z * rv[k].z + rv[k].w * rv[k].w;
    }
#pragma unroll
    for (int m = 1; m < 64; m <<= 1) {
      s += __shfl_xor(s, m, 64);
      ss += __shfl_xor(ss, m, 64);
    }
    const float mu = s * (1.0f / D_);
    const float var = ss * (1.0f / D_) - mu * mu;
    const float rstd = rsqrtf(var + 1e-5f);
    u16* drow = cln + (size_t)row * D_;
#pragma unroll
    for (int k = 0; k < 4; k++) {
      const float4 gv = ((const float4*)gamma)[k * 64 + lane];
      const float4 bv = ((const float4*)beta)[k * 64 + lane];
      ushort4 ov;
      ov.x = f2bf((rv[k].x - mu) * rstd * gv.x + bv.x);
      ov.y = f2bf((rv[k].y - mu) * rstd * gv.y + bv.y);
      ov.z = f2bf((rv[k].z - mu) * rstd * gv.z + bv.z);
      ov.w = f2bf((rv[k].w - mu) * rstd * gv.w + bv.w);
      ((ushort4*)drow)[k * 64 + lane] = ov;
    }
    return;
  }
  if (bx < 2048) {  // weight transpose slab (float4-vectorized)
    const int z = (bx - 1024) >> 8;
    const int rem = (bx - 1024) & 255;
    const float* in; u16* out;
    switch (z) {
      case 0:  in = W0; out = O0; break;
      case 1:  in = W1; out = O1; break;
      case 2:  in = W2; out = O2; break;
      default: in = W3; out = O3; break;
    }
    const int k0 = (rem & 15) * 64, n0 = (rem >> 4) * 64;
    const int c4 = t & 15, rr = t >> 4;     // 16 float4-cols x 16 rows per pass
#pragma unroll
    for (int p = 0; p < 4; p++) {
      const int i = rr + p * 16;
      float4 v = *(const float4*)&in[(size_t)(k0 + i) * D_ + n0 + c4 * 4];
      tile[i][c4 * 4 + 0] = f2bf(v.x);
      tile[i][c4 * 4 + 1] = f2bf(v.y);
      tile[i][c4 * 4 + 2] = f2bf(v.z);
      tile[i][c4 * 4 + 3] = f2bf(v.w);
    }
    __syncthreads();
#pragma unroll
    for (int p = 0; p < 4; p++) {
      const int i = rr + p * 16;
      ushort4 o;
      o.x = tile[c4 * 4 + 0][i];
      o.y = tile[c4 * 4 + 1][i];
      o.z = tile[c4 * 4 + 2][i];
      o.w = tile[c4 * 4 + 3][i];
      *(ushort4*)&out[(size_t)(n0 + i) * D_ + k0 + c4 * 4] = o;
    }
    return;
  }
  // pos f32 -> bf16, tiled: u enumerates (b, g, r, oct); 136 groups of 16 rows per batch
  {
    const int u = (bx - 2048) * 256 + t;    // [0, 34816)
    const int oct = u & 7;
    const int r = (u >> 3) & 15;
    const int g = (u >> 7) % 136;
    const int b = u / 17408;                // 136*128
    const int row = g * 16 + r;             // <= 2175 < R_ (always in-bounds)
    const float* s = pos + ((size_t)b * R_ + row) * 64 + oct * 8;
    float4 v0 = ((const float4*)s)[0];
    float4 v1 = ((const float4*)s)[1];
    ushort4 oA, oB;
    oA.x = f2bf(v0.x); oA.y = f2bf(v0.y); oA.z = f2bf(v0.z); oA.w = f2bf(v0.w);
    oB.x = f2bf(v1.x); oB.y = f2bf(v1.y); oB.z = f2bf(v1.z); oB.w = f2bf(v1.w);
    u16* d = posT + (size_t)(b * 144 + g) * 1024 + oct * 128 + r * 8;  // 144-group stride
    ((ushort4*)d)[0] = oA;
    ((ushort4*)d)[1] = oB;
  }
}

// row r of the "hidden slice" view -> row of c_ln
__device__ __forceinline__ int maprow_hidden(int r) {
  return r + ((r >> 10) << 10) + M_;
}

// ---------------- QKV GEMM: BK=64, XOR-swizzled staging, 3 blocks/CU ----------------
// NEW: XCD-banded live-tile remap (grid = 640, only live tiles dispatched).
// dispatch i -> XCD i%8. mem-band XCDs {0,1,4,5}: their 4-row KV band (64 tiles)
// + 16 Q-tiles borrowed from the paired hidden band (+2). hidden-band XCDs
// {2,3,6,7}: their band minus those Q-tiles (80 each). Per-XCD A working set
// 8 MB -> ~1.5 MB (L2-resident). Bijective over the 640 live tiles.
// LDS-staged coalesced epilogue (R11) + fragment-tiled V (R12).
__global__ __launch_bounds__(256, 3) void gemm_qkv_kernel(
    const u16* __restrict__ A, const u16* __restrict__ Bt,
    u16* __restrict__ qb, u16* __restrict__ kb, u16* __restrict__ vf) {
  __shared__ __align__(16) u16 shm[128 * 132];   // 33 KB: As|Bs during loop, C-tile after
  u16* As = shm;                 // 128*64
  u16* Bs = shm + 8192;          // 128*64
  const int t = threadIdx.x;
  const int lane = t & 63, w = t >> 6;
  const int wm = w >> 1, wn = w & 1;
  const int qd = lane >> 4, lr = lane & 15;

  // XCD-banded remap of the 640 live tiles
  const int l = blockIdx.x;
  const int xcd = l & 7;
  const int j = l >> 3;                // 0..79
  int by, bx;
  if ((xcd & 2) == 0) {                // mem-band XCDs 0,1,4,5 (rows all-memory)
    if (j < 64) { by = xcd * 4 + (j >> 4); bx = 8 + (j & 15); }
    else { const int j2 = j - 64; by = (xcd + 2) * 4 + (j2 >> 3); bx = j2 & 7; }
  } else {                             // hidden-band XCDs 2,3,6,7
    if (j < 32) { by = xcd * 4 + (j >> 4); bx = 8 + (j & 15); }
    else { const int j2 = j - 32; by = xcd * 4 + 2 + j2 / 24; bx = j2 % 24; }
  }
  const int m0 = by * 128, n0 = bx * 128;

  const int swz = ((t & 7) ^ ((t >> 3) & 7)) * 8;  // source-chunk swizzle
  const int c0 = (qd ^ (lr & 7)) * 8;
  const int c1 = c0 ^ 32;
  const int row8 = (t >> 3) & 7;

  f32x4 acc[4][4];
#pragma unroll
  for (int mt = 0; mt < 4; mt++)
#pragma unroll
    for (int nt = 0; nt < 4; nt++) acc[mt][nt] = (f32x4){0.f, 0.f, 0.f, 0.f};

  for (int kt = 0; kt < 1024; kt += 64) {
#pragma unroll
    for (int p = 0; p < 4; p++) {
      const int ra = w * 32 + p * 8 + row8;
      gll16(A + (size_t)(m0 + ra) * 1024 + kt + swz, As + (w * 32 + p * 8) * 64);
      gll16(Bt + (size_t)(n0 + ra) * 1024 + kt + swz, Bs + (w * 32 + p * 8) * 64);
    }
    __syncthreads();
    short8 a0[4], a1[4], b0[4], b1[4];
#pragma unroll
    for (int mt = 0; mt < 4; mt++) {
      a0[mt] = *(const short8*)&As[(wm * 64 + mt * 16 + lr) * 64 + c0];
      a1[mt] = *(const short8*)&As[(wm * 64 + mt * 16 + lr) * 64 + c1];
    }
#pragma unroll
    for (int nt = 0; nt < 4; nt++) {
      b0[nt] = *(const short8*)&Bs[(wn * 64 + nt * 16 + lr) * 64 + c0];
      b1[nt] = *(const short8*)&Bs[(wn * 64 + nt * 16 + lr) * 64 + c1];
    }
#pragma unroll
    for (int mt = 0; mt < 4; mt++)
#pragma unroll
      for (int nt = 0; nt < 4; nt++) {
        acc[mt][nt] = mfma16(a0[mt], b0[nt], acc[mt][nt]);
        acc[mt][nt] = mfma16(a1[mt], b1[nt], acc[mt][nt]);
      }
    __syncthreads();
  }

  // ---- epilogue: stage C-tile (or C^T for V) into LDS, then coalesced stores ----
  const bool isV = (n0 >= 2048);
  if (!isV) {                    // Q (scaled) or K: row-major [row][col], pad 132
    const float sc = (n0 < 1024) ? 0.03125f : 1.0f;
#pragma unroll
    for (int mt = 0; mt < 4; mt++)
#pragma unroll
      for (int nt = 0; nt < 4; nt++) {
        const int row0 = wm * 64 + mt * 16 + qd * 4;
        const int col = wn * 64 + nt * 16 + lr;
#pragma unroll
        for (int r = 0; r < 4; r++)
          shm[(row0 + r) * 132 + col] = f2bf(acc[mt][nt][r] * sc);
      }
  } else {                       // V: transposed [nn][kk], ushort4 along kk
#pragma unroll
    for (int mt = 0; mt < 4; mt++)
#pragma unroll
      for (int nt = 0; nt < 4; nt++) {
        const int kk0 = wm * 64 + mt * 16 + qd * 4;
        const int nn = wn * 64 + nt * 16 + lr;
        ushort4 pk;
        pk.x = f2bf(acc[mt][nt][0]);
        pk.y = f2bf(acc[mt][nt][1]);
        pk.z = f2bf(acc[mt][nt][2]);
        pk.w = f2bf(acc[mt][nt][3]);
        *(ushort4*)&shm[nn * 132 + kk0] = pk;
      }
  }
  __syncthreads();
  // 2048 16B-chunks (128 rows x 16), 8 per thread; consecutive t -> contiguous runs
  const int bq = m0 >> 11;
#pragma unroll
  for (int i = 0; i < 8; i++) {
    const int flat = i * 256 + t;
    const int row = flat >> 4;
    const int ch = flat & 15;
    const ushort4 v0 = *(const ushort4*)&shm[row * 132 + ch * 8];
    const ushort4 v1 = *(const ushort4*)&shm[row * 132 + ch * 8 + 4];
    u16* dst;
    if (n0 < 1024) {
      const int qrow = (bq << 10) | ((m0 + row) & 1023);
      dst = qb + (size_t)qrow * 1024 + n0 + ch * 8;
    } else if (!isV) {
      const int key = (m0 + row) & (K_ - 1);
      dst = kb + (size_t)(bq * K_ + key) * 1024 + (n0 - 1024) + ch * 8;
    } else {
      // fragment-tiled vf: row = dh within 128-col block, chunk = 8 keys
      const int dhg = (n0 - 2048) + row;           // h*64 + dh within batch
      const int bh = (bq << 4) | (dhg >> 6);
      const int dh = dhg & 63;
      const int gk = (m0 & (K_ - 1)) + ch * 8;     // global key of this chunk
      const int ktile = gk >> 6;
      const int w6ch = (gk & 63) >> 3;
      const int d2 = dh >> 4, lrr = dh & 15;
      dst = vf + (size_t)bh * 131072 + (size_t)ktile * 4096
               + ((d2 * 8 + w6ch) * 16 + lrr) * 8;
    }
    short8 vv;
    *(ushort4*)&vv = v0;
    *(((ushort4*)&vv) + 1) = v1;
    *(short8*)dst = vv;          // one 16B store
  }
}

// ---------------- out GEMM: 64x64 tiles, XCD-banded remap (4 rows x 16 cols/XCD) -------
// BK=64, XOR-swizzled. grid 512 (1-D).
__global__ __launch_bounds__(256, 2) void out_gemm_kernel(
    const u16* __restrict__ A, const u16* __restrict__ Bt,
    const u16* __restrict__ resid, float* __restrict__ Cf) {
  __shared__ __align__(16) u16 As[64 * 64];    // 8 KB
  __shared__ __align__(16) u16 Bs[64 * 64];    // 8 KB
  const int t = threadIdx.x;
  const int lane = t & 63, w = t >> 6;
  const int wm = w >> 1, wn = w & 1;
  const int qd = lane >> 4, lr = lane & 15;

  const int flat = blockIdx.x;
  const int xcd = flat & 7;
  const int idx = flat >> 3;           // 0..63
  const int by = xcd * 4 + (idx >> 4);
  const int bxx = idx & 15;
  const int m0 = by * 64, n0 = bxx * 64;

  const int swz = ((t & 7) ^ ((t >> 3) & 7)) * 8;  // source-chunk swizzle
  const int c0 = (qd ^ (lr & 7)) * 8;              // fragment-read chunk offsets
  const int c1 = c0 ^ 32;
  const int row8 = (t >> 3) & 7;

  f32x4 acc[2][2];
#pragma unroll
  for (int mt = 0; mt < 2; mt++)
#pragma unroll
    for (int nt = 0; nt < 2; nt++) acc[mt][nt] = (f32x4){0.f, 0.f, 0.f, 0.f};

  for (int kt = 0; kt < 1024; kt += 64) {
#pragma unroll
    for (int p = 0; p < 2; p++) {
      const int ra = w * 16 + p * 8 + row8;
      gll16(A + (size_t)(m0 + ra) * 1024 + kt + swz, As + (w * 16 + p * 8) * 64);
      gll16(Bt + (size_t)(n0 + ra) * 1024 + kt + swz, Bs + (w * 16 + p * 8) * 64);
    }
    __syncthreads();
    short8 a0[2], a1[2], b0[2], b1[2];
#pragma unroll
    for (int mt = 0; mt < 2; mt++) {
      a0[mt] = *(const short8*)&As[(wm * 32 + mt * 16 + lr) * 64 + c0];
      a1[mt] = *(const short8*)&As[(wm * 32 + mt * 16 + lr) * 64 + c1];
    }
#pragma unroll
    for (int nt = 0; nt < 2; nt++) {
      b0[nt] = *(const short8*)&Bs[(wn * 32 + nt * 16 + lr) * 64 + c0];
      b1[nt] = *(const short8*)&Bs[(wn * 32 + nt * 16 + lr) * 64 + c1];
    }
#pragma unroll
    for (int mt = 0; mt < 2; mt++)
#pragma unroll
      for (int nt = 0; nt < 2; nt++) {
        acc[mt][nt] = mfma16(a0[mt], b0[nt], acc[mt][nt]);
        acc[mt][nt] = mfma16(a1[mt], b1[nt], acc[mt][nt]);
      }
    __syncthreads();
  }

#pragma unroll
  for (int mt = 0; mt < 2; mt++)
#pragma unroll
    for (int nt = 0; nt < 2; nt++)
#pragma unroll
      for (int r = 0; r < 4; r++) {
        const int row = m0 + wm * 32 + mt * 16 + qd * 4 + r;
        const int col = n0 + wn * 32 + nt * 16 + lr;
        float v = acc[mt][nt][r] + bf2f(resid[(size_t)maprow_hidden(row) * 1024 + col]);
        Cf[(size_t)row * 1024 + col] = v;
      }
}

// ---------------- attention: KVBLK=128, V DIRECT FROM L2 (no LDS staging) --------------
// R12-proven; byte-identical. grid (16, H, B).
__global__ __launch_bounds__(256, 2) void attn_kernel(
    const u16* __restrict__ qb, const u16* __restrict__ kb,
    const u16* __restrict__ vf, const u16* __restrict__ posT,
    u16* __restrict__ ab) {
  __shared__ __align__(16) u16 Ks[2][2][64 * 64];   // 32 KB (Ks[1][0] aliases Q pre-loop)
  __shared__ __align__(16) u16 Pt[4][16 * 64];      // 8 KB wave-private (XOR-swizzled)

  const int t = threadIdx.x;
  const int lane = t & 63, w = t >> 6;
  const int qd = lane >> 4, lr = lane & 15;

  // XCD-grouping remap (bijective on 512 blocks) — R4-proven
  const int flat = blockIdx.x + 16 * blockIdx.y + 256 * blockIdx.z;
  const int xcd = flat & 7;
  const int slot = flat >> 3;          // 0..63 within XCD
  const int gsub = slot >> 4;          // 0..3
  int qt = slot & 15;
  if (gsub & 2) qt = 15 - qt;          // complementary pairing on each CU
  const int g = gsub * 8 + xcd;        // (b,h) group 0..31
  const int h = g & 15;
  const int b = g >> 4;
  const int i0 = qt * 64;

  const int swz = ((t & 7) ^ ((t >> 3) & 7)) * 8;  // staging source-chunk swizzle
  const int c0 = (qd ^ (lr & 7)) * 8;              // fragment-read chunk offsets
  const int c1 = c0 ^ 32;
  const int row8 = t >> 3;

  const int jmax = min(K_, i0 + 64 + M_);

  // tiled pos fragment base: group for 64-key sub tt, frag pc is g0 + 4*tt + pc.
  const int g0 = 63 - (i0 >> 4) - w;
  const u16* pb0 = posT + (size_t)b * 147456 + qd * 128 + lr * 8;
  // fragment-tiled V base for this (b,h); per-lane fragment offsets
  const u16* vfb = vf + (size_t)(b * H_ + h) * 131072 + lr * 8;

  // ---- pre-loop staging: Q -> Ks[1][0]; phase0 K (both subs) -> buf0 ----
#pragma unroll
  for (int rd = 0; rd < 2; rd++)
    gll16(qb + (size_t)(b * S_ + i0 + rd * 32 + row8) * 1024 + h * 64 + swz,
          &Ks[1][0][0] + rd * 2048 + w * 512);
#pragma unroll
  for (int sb = 0; sb < 2; sb++)
#pragma unroll
    for (int rd = 0; rd < 2; rd++)
      gll16(kb + (size_t)(b * K_ + sb * 64 + rd * 32 + row8) * 1024 + h * 64 + swz,
            &Ks[0][sb][0] + rd * 2048 + w * 512);
  // preload pos fragments for phase0 subs (registers, coalesced)
  short8 pgA0[5], pgA1[5], pgB0[5], pgB1[5];
  {
    const u16* pp = pb0 + (size_t)g0 * 1024;
#pragma unroll
    for (int pc = 0; pc < 5; pc++) {
      pgA0[pc] = *(const short8*)(pp + pc * 1024);
      pgA1[pc] = *(const short8*)(pp + pc * 1024 + 512);
    }
    const u16* p2 = pb0 + (size_t)(g0 + 4) * 1024;
#pragma unroll
    for (int pc = 0; pc < 5; pc++) {
      pgB0[pc] = *(const short8*)(p2 + pc * 1024);
      pgB1[pc] = *(const short8*)(p2 + pc * 1024 + 512);
    }
  }
  __syncthreads();
  const short8 aQ0 = *(const short8*)&Ks[1][0][(w * 16 + lr) * 64 + c0];
  const short8 aQ1 = *(const short8*)&Ks[1][0][(w * 16 + lr) * 64 + c1];

  f32x4 accO[4];
#pragma unroll
  for (int d = 0; d < 4; d++) accO[d] = (f32x4){0.f, 0.f, 0.f, 0.f};
  float lsum[4];
#pragma unroll
  for (int r = 0; r < 4; r++) lsum[r] = 0.f;

  for (int j0 = 0, ph = 0; j0 < jmax; j0 += 128, ph++) {
    __syncthreads();
    const int cb = ph & 1;
    const int nb = cb ^ 1;
    const int j0n = j0 + 128;
    // ---- stage phase+1 K (per-sub guard; valid subs are fully in-bounds) ----
#pragma unroll
    for (int sb = 0; sb < 2; sb++)
      if (j0n + sb * 64 < jmax) {
#pragma unroll
        for (int rd = 0; rd < 2; rd++)
          gll16(kb + (size_t)(b * K_ + j0n + sb * 64 + rd * 32 + row8) * 1024 + h * 64 + swz,
                &Ks[nb][sb][0] + rd * 2048 + w * 512);
      }

    // ================= SUB 0 (keys j0 .. j0+63) =================
    {
      // V fragments direct from L2 (coalesced 1KB each); latency hides under QK+softmax
      const u16* vtp = vfb + (size_t)(j0 >> 6) * 4096;
      short8 vA[4], vB[4];
#pragma unroll
      for (int d2 = 0; d2 < 4; d2++) {
        vA[d2] = *(const short8*)(vtp + (d2 * 8 + qd) * 128);
        vB[d2] = *(const short8*)(vtp + (d2 * 8 + qd + 4) * 128);
      }
      __builtin_amdgcn_s_setprio(1);
      f32x4 zp[5];
#pragma unroll
      for (int pc = 0; pc < 5; pc++) {
        f32x4 z = {0.f, 0.f, 0.f, 0.f};
        z = mfma16(aQ0, pgA0[pc], z);
        zp[pc] = mfma16(aQ1, pgA1[pc], z);
      }
      f32x4 sqk[4];
#pragma unroll
      for (int kc = 0; kc < 4; kc++) {
        const short8 bK0 = *(const short8*)&Ks[cb][0][(kc * 16 + lr) * 64 + c0];
        const short8 bK1 = *(const short8*)&Ks[cb][0][(kc * 16 + lr) * 64 + c1];
        f32x4 z = {0.f, 0.f, 0.f, 0.f};
        z = mfma16(aQ0, bK0, z);
        sqk[kc] = mfma16(aQ1, bK1, z);
      }
      __builtin_amdgcn_s_setprio(0);
      // prefetch pgA for next phase's sub0 (tt = 2*ph+2)
      {
        const u16* pn = pb0 + (size_t)(g0 + 4 * (2 * ph + 2)) * 1024;
#pragma unroll
        for (int pc = 0; pc < 5; pc++) {
          pgA0[pc] = *(const short8*)(pn + pc * 1024);
          pgA1[pc] = *(const short8*)(pn + pc * 1024 + 512);
        }
      }
      // shuffle-based skew gather + max-free softmax
      const bool tail = (j0 + 63 > i0 + w * 16 + M_);
      float p[4][4];
#pragma unroll
      for (int r = 0; r < 4; r++) {
        const int iL = qd * 4 + r;
        const int d = 15 + lr - iL;
        const int srcl = qd * 16 + (d & 15);
        const bool hi = (d >> 4) & 1;
        float g0s = __shfl(zp[0][r], srcl, 64);
        float g1s = __shfl(zp[1][r], srcl, 64);
        float g2s = __shfl(zp[2][r], srcl, 64);
        float g3s = __shfl(zp[3][r], srcl, 64);
        float g4s = __shfl(zp[4][r], srcl, 64);
        float s0 = sqk[0][r] + (hi ? g1s : g0s);
        float s1 = sqk[1][r] + (hi ? g2s : g1s);
        float s2 = sqk[2][r] + (hi ? g3s : g2s);
        float s3 = sqk[3][r] + (hi ? g4s : g3s);
        if (tail) {
          const int key = j0 + lr, lim = i0 + w * 16 + iL + M_;
          if (key      > lim) s0 = NEG_BIG;
          if (key + 16 > lim) s1 = NEG_BIG;
          if (key + 32 > lim) s2 = NEG_BIG;
          if (key + 48 > lim) s3 = NEG_BIG;
        }
        p[0][r] = __expf(s0);
        p[1][r] = __expf(s1);
        p[2][r] = __expf(s2);
        p[3][r] = __expf(s3);
        lsum[r] += p[0][r] + p[1][r] + p[2][r] + p[3][r];
      }
      // P -> wave-private LDS (XOR chunk swizzle) -> A-fragments
#pragma unroll
      for (int r = 0; r < 4; r++) {
        const int row = qd * 4 + r;
        const int cbase = row * 64;
        const int rx = row & 7;
        const int lo = lr & 7, hi8 = lr >> 3;
#pragma unroll
        for (int kc = 0; kc < 4; kc++)
          Pt[w][cbase + ((((kc << 1) | hi8) ^ rx) << 3) + lo] = f2bf(p[kc][r]);
      }
      __asm__ volatile("s_waitcnt lgkmcnt(0)" ::: "memory");
      const short8 aP0 = *(const short8*)&Pt[w][lr * 64 + ((qd ^ (lr & 7)) << 3)];
      const short8 aP1 = *(const short8*)&Pt[w][lr * 64 + (((qd + 4) ^ (lr & 7)) << 3)];
      // P @ V (register fragments)
      __builtin_amdgcn_s_setprio(1);
#pragma unroll
      for (int d2 = 0; d2 < 4; d2++) {
        accO[d2] = mfma16(aP0, vA[d2], accO[d2]);
        accO[d2] = mfma16(aP1, vB[d2], accO[d2]);
      }
      __builtin_amdgcn_s_setprio(0);
    }

    // ================= SUB 1 (keys j0+64 .. j0+127) =================
    if (j0 + 64 < jmax) {
      const int j1 = j0 + 64;
      const u16* vtp = vfb + (size_t)(j1 >> 6) * 4096;
      short8 vA[4], vB[4];
#pragma unroll
      for (int d2 = 0; d2 < 4; d2++) {
        vA[d2] = *(const short8*)(vtp + (d2 * 8 + qd) * 128);
        vB[d2] = *(const short8*)(vtp + (d2 * 8 + qd + 4) * 128);
      }
      __builtin_amdgcn_s_setprio(1);
      f32x4 zp[5];
#pragma unroll
      for (int pc = 0; pc < 5; pc++) {
        f32x4 z = {0.f, 0.f, 0.f, 0.f};
        z = mfma16(aQ0, pgB0[pc], z);
        zp[pc] = mfma16(aQ1, pgB1[pc], z);
      }
      f32x4 sqk[4];
#pragma unroll
      for (int kc = 0; kc < 4; kc++) {
        const short8 bK0 = *(const short8*)&Ks[cb][1][(kc * 16 + lr) * 64 + c0];
        const short8 bK1 = *(const short8*)&Ks[cb][1][(kc * 16 + lr) * 64 + c1];
        f32x4 z = {0.f, 0.f, 0.f, 0.f};
        z = mfma16(aQ0, bK0, z);
        sqk[kc] = mfma16(aQ1, bK1, z);
      }
      __builtin_amdgcn_s_setprio(0);
      // prefetch pgB for next phase's sub1 (tt = 2*ph+3)
      {
        const u16* pn = pb0 + (size_t)(g0 + 4 * (2 * ph + 3)) * 1024;
#pragma unroll
        for (int pc = 0; pc < 5; pc++) {
          pgB0[pc] = *(const short8*)(pn + pc * 1024);
          pgB1[pc] = *(const short8*)(pn + pc * 1024 + 512);
        }
      }
      const bool tail = (j1 + 63 > i0 + w * 16 + M_);
      float p[4][4];
#pragma unroll
      for (int r = 0; r < 4; r++) {
        const int iL = qd * 4 + r;
        const int d = 15 + lr - iL;
        const int srcl = qd * 16 + (d & 15);
        const bool hi = (d >> 4) & 1;
        float g0s = __shfl(zp[0][r], srcl, 64);
        float g1s = __shfl(zp[1][r], srcl, 64);
        float g2s = __shfl(zp[2][r], srcl, 64);
        float g3s = __shfl(zp[3][r], srcl, 64);
        float g4s = __shfl(zp[4][r], srcl, 64);
        float s0 = sqk[0][r] + (hi ? g1s : g0s);
        float s1 = sqk[1][r] + (hi ? g2s : g1s);
        float s2 = sqk[2][r] + (hi ? g3s : g2s);
        float s3 = sqk[3][r] + (hi ? g4s : g3s);
        if (tail) {
          const int key = j1 + lr, lim = i0 + w * 16 + iL + M_;
          if (key      > lim) s0 = NEG_BIG;
          if (key + 16 > lim) s1 = NEG_BIG;
          if (key + 32 > lim) s2 = NEG_BIG;
          if (key + 48 > lim) s3 = NEG_BIG;
        }
        p[0][r] = __expf(s0);
        p[1][r] = __expf(s1);
        p[2][r] = __expf(s2);
        p[3][r] = __expf(s3);
        lsum[r] += p[0][r] + p[1][r] + p[2][r] + p[3][r];
      }
#pragma unroll
      for (int r = 0; r < 4; r++) {
        const int row = qd * 4 + r;
        const int cbase = row * 64;
        const int rx = row & 7;
        const int lo = lr & 7, hi8 = lr >> 3;
#pragma unroll
        for (int kc = 0; kc < 4; kc++)
          Pt[w][cbase + ((((kc << 1) | hi8) ^ rx) << 3) + lo] = f2bf(p[kc][r]);
      }
      __asm__ volatile("s_waitcnt lgkmcnt(0)" ::: "memory");
      const short8 aP0 = *(const short8*)&Pt[w][lr * 64 + ((qd ^ (lr & 7)) << 3)];
      const short8 aP1 = *(const short8*)&Pt[w][lr * 64 + (((qd + 4) ^ (lr & 7)) << 3)];
      __builtin_amdgcn_s_setprio(1);
#pragma unroll
      for (int d2 = 0; d2 < 4; d2++) {
        accO[d2] = mfma16(aP0, vA[d2], accO[d2]);
        accO[d2] = mfma16(aP1, vB[d2], accO[d2]);
      }
      __builtin_amdgcn_s_setprio(0);
    }
  }

  // ---- epilogue: one 16-lane reduction of lsum, then normalize ----
  float inv[4];
#pragma unroll
  for (int r = 0; r < 4; r++) {
#pragma unroll
    for (int msk = 1; msk < 16; msk <<= 1) lsum[r] += __shfl_xor(lsum[r], msk, 64);
    inv[r] = 1.0f / lsum[r];
  }
#pragma unroll
  for (int d2 = 0; d2 < 4; d2++)
#pragma unroll
    for (int r = 0; r < 4; r++) {
      const int iG = i0 + w * 16 + qd * 4 + r;
      ab[(size_t)(b * S_ + iG) * 1024 + h * 64 + d2 * 16 + lr] = f2bf(accO[d2][r] * inv[r]);
    }
}

// ---------------- launch ----------------
extern "C" void kernel_launch(void* const* d_in, const int* in_sizes, int n_in,
                              void* d_out, int out_size, void* d_ws, size_t ws_size,
                              hipStream_t stream) {
  const float* hidden = (const float*)d_in[0];
  const float* pos    = (const float*)d_in[1];
  const float* memory = (const float*)d_in[2];
  // d_in[3] = mask (bool) — causality applied analytically, unused
  const float* Wq = (const float*)d_in[4];
  const float* Wk = (const float*)d_in[5];
  const float* Wv = (const float*)d_in[6];
  const float* Wo = (const float*)d_in[7];
  const float* gamma = (const float*)d_in[8];
  const float* beta  = (const float*)d_in[9];

  char* ws = (char*)d_ws;
  u16* cln  = (u16*)(ws);               // 8 MB
  u16* qb   = (u16*)(ws + 8388608);     // 4 MB (pre-scaled 1/32)
  u16* kb   = (u16*)(ws + 12582912);    // 8 MB
  u16* vf   = (u16*)(ws + 20971520);    // 8 MB fragment-tiled V
  u16* ab   = (u16*)(ws + 29360128);    // 4 MB
  u16* WqT  = (u16*)(ws + 33554432);    // 4 x 2 MB contiguous (WqT|WkT|WvT|WoT)
  u16* WkT  = WqT + 1048576;
  u16* WvT  = WkT + 1048576;
  u16* WoT  = WvT + 1048576;
  u16* posT = (u16*)(ws + 41943040);    // 0.56 MB tiled pos (144-group stride)

  prep_kernel<<<dim3(2184), 256, 0, stream>>>(
      hidden, memory, gamma, beta, cln,
      Wq, Wk, Wv, Wo, WqT, WkT, WvT, WoT, pos, posT);
  gemm_qkv_kernel<<<dim3(640), 256, 0, stream>>>(cln, WqT, qb, kb, vf);
  attn_kernel<<<dim3(S_ / 64, H_, B_), 256, 0, stream>>>(qb, kb, vf, posT, ab);
  out_gemm_kernel<<<dim3(512), 256, 0, stream>>>(ab, WoT, cln, (float*)d_out);
}